// Round 12
// baseline (7093.246 us; speedup 1.0000x reference)
//
#include <hip/hip_runtime.h>
#include <hip/hip_bf16.h>

#define AGENT __HIP_MEMORY_SCOPE_AGENT

typedef float f32x4 __attribute__((ext_vector_type(4)));
typedef short short8 __attribute__((ext_vector_type(8)));
union V16 { f32x4 f; short8 s; };

// B=64 S=512 T=96 E=256 H=512 ENC_DIM=1024 4H=2048

__device__ __forceinline__ float sigm(float x){ return 1.f/(1.f+__expf(-x)); }
__device__ __forceinline__ float tanhfast(float x){
  float ax = fabsf(x);
  float e = __expf(-2.f*ax);
  float r = (1.f-e)/(1.f+e);
  return copysignf(r, x);
}
__device__ __forceinline__ float dot4(float4 a, float4 b){
  return fmaf(a.x,b.x, fmaf(a.y,b.y, fmaf(a.z,b.z, a.w*b.w)));
}
__device__ __forceinline__ unsigned short bfbits(float x){
  return __bfloat16_as_ushort(__float2bfloat16(x));
}
__device__ __forceinline__ float bfu2f(unsigned short u){
  union{unsigned v; float f;} x; x.v = ((unsigned)u)<<16; return x.f;
}

// ---------------- precompute ----------------
__global__ void __launch_bounds__(256) precompute(
  const float* __restrict__ Wenc,
  const float* __restrict__ Wihf, const float* __restrict__ epW, const float* __restrict__ epb,
  const float* __restrict__ bihf, const float* __restrict__ bhhf,
  const float* __restrict__ Wihb, const float* __restrict__ bihb, const float* __restrict__ bhhb,
  const float* __restrict__ dWih, const float* __restrict__ dpW, const float* __restrict__ dpb,
  const float* __restrict__ dbih, const float* __restrict__ dbhh,
  const float* __restrict__ valW, const float* __restrict__ valb,
  const float* __restrict__ stopW, const float* __restrict__ stopb,
  float* __restrict__ PQ, float* __restrict__ WT, float* __restrict__ hc)
{
  const int idx = blockIdx.x*256 + threadIdx.x;
  if (idx < 524288){
    const int j = idx >> 9, n = idx & 511;
    WT[idx] = Wenc[(size_t)n*1024 + j];
  } else if (idx < 524288 + 6*2048){
    const int q = idx - 524288;
    const int set = q >> 11, j = q & 2047;
    const float* row; const float* vec; float add = 0.f;
    switch(set){
      case 0: row = Wihf + (size_t)j*256; vec = epW; break;
      case 1: row = Wihf + (size_t)j*256; vec = epb; add = bihf[j]+bhhf[j]; break;
      case 2: row = Wihb + (size_t)j*256; vec = epW; break;
      case 3: row = Wihb + (size_t)j*256; vec = epb; add = bihb[j]+bhhb[j]; break;
      case 4: row = dWih + (size_t)j*1280; vec = dpW; break;
      default: row = dWih + (size_t)j*1280; vec = dpb; add = dbih[j]+dbhh[j]; break;
    }
    float a = add;
    for (int e=0;e<256;e++) a = fmaf(row[e], vec[e], a);
    PQ[set*2048 + j] = a;
  } else if (idx < 524288 + 6*2048 + 4){
    const int q = idx - (524288 + 6*2048);
    const float* wrow = (q<2) ? valW : stopW;
    const float* vec  = (q&1) ? dpb : dpW;
    float a = (q&1) ? ((q<2)? valb[0] : stopb[0]) : 0.f;
    for (int e=0;e<256;e++) a = fmaf(wrow[1536+e], vec[e], a);
    hc[q] = a;
  }
}

// ---------------- weight converts ----------------
__global__ void __launch_bounds__(512) wconv(
  const float* __restrict__ Whhf, const float* __restrict__ Whhb,
  const float* __restrict__ dWih, const float* __restrict__ dWhh,
  const float* __restrict__ Wdec, const float* __restrict__ Wenc,
  unsigned short* __restrict__ Wbf, unsigned short* __restrict__ Wcat,
  unsigned short* __restrict__ Wdecb, unsigned short* __restrict__ Wencb)
{
  const int i = blockIdx.x*512 + threadIdx.x;
  if (i < 2097152){
    const float v = (i < 1048576) ? Whhf[i] : Whhb[i-1048576];
    Wbf[i] = bfbits(v);
  } else if (i < 2097152+3145728){
    const int q = i - 2097152;
    const int r = q/1536, k = q - r*1536;
    const float v = (k<1024) ? dWih[(size_t)r*1280 + 256 + k] : dWhh[(size_t)r*512 + (k-1024)];
    Wcat[q] = bfbits(v);
  } else if (i < 2097152+3145728+262144){
    const int q = i - (2097152+3145728);
    Wdecb[q] = bfbits(Wdec[q]);   // row-major [j][u]
  } else if (i < 2097152+3145728+262144+524288){
    const int q = i - (2097152+3145728+262144);
    Wencb[q] = bfbits(Wenc[q]);   // row-major [n][k]
  }
}

// ---------------- encoder (unchanged, proven) ----------------
__global__ void __launch_bounds__(512) enc_mfma(
    const float* __restrict__ src, const int* __restrict__ smask,
    const unsigned short* __restrict__ Wbf,
    const float* __restrict__ PQ,
    unsigned short* __restrict__ hbuf,
    float* __restrict__ hfin,
    float* __restrict__ cf, float* __restrict__ cb,
    __hip_bfloat16* __restrict__ enc,
    unsigned* __restrict__ cnt)
{
  __shared__ float hlds[16*256];
  __shared__ float red[4*64*4];
  __shared__ float gbuf[4*256];
  __shared__ alignas(16) unsigned short hstage[256];
  __shared__ alignas(16) unsigned short estage[256];

  const int tid = threadIdx.x;
  const int bid = blockIdx.x;
  const int dir = bid>>7, bhalf = (bid>>5)&3, us = bid&31;
  const int b0 = bhalf*16;
  unsigned* gcnt = cnt + (dir*4 + bhalf)*32;
  const int wv = tid>>6, lane = tid&63;
  const int nt = wv&3, kh = wv>>2;
  const int rowb = lane&15;

  short8 bfr[8];
  {
    const int g = nt*512 + us*16 + (lane&15);
    const unsigned short* wp = Wbf + ((size_t)dir*2048 + g)*512 + kh*256 + (lane>>4)*8;
    #pragma unroll
    for (int kt=0;kt<8;kt++) bfr[kt] = *(const short8*)(wp + kt*32);
  }

  float p0=0,p1=0,p2=0,p3=0,q0=0,q1=0,q2=0,q3=0;
  float creg = 0.f, hprev = 0.f;
  int bg = 0, ug = 0;
  if (tid < 256){
    bg = b0 + (tid>>4);
    ug = us*16 + (tid&15);
    const float* P = PQ + dir*4096; const float* Q = P + 2048;
    p0=P[ug]; p1=P[ug+512]; p2=P[ug+1024]; p3=P[ug+1536];
    q0=Q[ug]; q1=Q[ug+512]; q2=Q[ug+1024]; q3=Q[ug+1536];
  }

  for (int tt=0; tt<512; ++tt){
    const int t = dir ? (511-tt) : tt;
    if (tt>0){
      if (tid==0){
        while (__hip_atomic_load(gcnt, __ATOMIC_RELAXED, AGENT) < 32u*(unsigned)tt)
          __builtin_amdgcn_s_sleep(1);
      }
      __syncthreads();
      const int par = (tt-1)&1;
      f32x4 tmp0, tmp1;
      {
        const int f0 = tid, f1 = 512 + tid;
        const unsigned short* g0 = hbuf + (((size_t)(dir*2+par)*64 + b0 + (f0>>6))<<9) + (f0&63)*8;
        const unsigned short* g1 = hbuf + (((size_t)(dir*2+par)*64 + b0 + (f1>>6))<<9) + (f1&63)*8;
        asm volatile("global_load_dwordx4 %0, %1, off sc0 sc1" : "=v"(tmp0) : "v"(g0) : "memory");
        asm volatile("global_load_dwordx4 %0, %1, off sc0 sc1" : "=v"(tmp1) : "v"(g1) : "memory");
      }
      asm volatile("s_waitcnt vmcnt(0)" ::: "memory");
      __builtin_amdgcn_sched_barrier(0);
      {
        const int r0 = tid>>6, c0 = tid&63;
        *(f32x4*)&hlds[r0*256 + ((c0 ^ (r0&7))<<2)] = tmp0;
        const int r1 = (512+tid)>>6, c1 = tid&63;
        *(f32x4*)&hlds[r1*256 + ((c1 ^ (r1&7))<<2)] = tmp1;
      }
      __syncthreads();
    }

    f32x4 acc = {0.f,0.f,0.f,0.f};
    if (tt>0){
      #pragma unroll
      for (int kt=0; kt<8; ++kt){
        const int ch = (kh*8 + kt)*4 + (lane>>4);
        V16 a; a.f = *(const f32x4*)&hlds[rowb*256 + ((ch ^ (rowb&7))<<2)];
        acc = __builtin_amdgcn_mfma_f32_16x16x32_bf16(a.s, bfr[kt], acc, 0, 0, 0);
      }
    }
    if (kh==1) *(f32x4*)&red[(nt*64+lane)*4] = acc;
    __syncthreads();
    if (kh==0){
      const f32x4 o = *(const f32x4*)&red[(nt*64+lane)*4];
      #pragma unroll
      for (int i=0;i<4;i++){
        const int r = (lane>>4)*4 + i, c = lane&15;
        gbuf[nt*256 + r*16 + c] = acc[i] + o[i];
      }
    }
    __syncthreads();

    if (tid < 256){
      const float sx = src[bg*512+t]*0.001f;
      const int m = smask[bg*512+t];
      const float gi = gbuf[0*256+tid] + sx*p0 + q0;
      const float gf = gbuf[1*256+tid] + sx*p1 + q1;
      const float gg = gbuf[2*256+tid] + sx*p2 + q2;
      const float go = gbuf[3*256+tid] + sx*p3 + q3;
      const float cn = fmaf(sigm(gf), creg, sigm(gi)*tanhfast(gg));
      const float hn = sigm(go)*tanhfast(cn);
      const float hk = m ? hn : hprev;
      creg = m ? cn : creg;
      hprev = hk;
      hstage[tid] = bfbits(hk);
      estage[tid] = bfbits(m ? hn : 0.f);
    }
    __syncthreads();
    if (tid < 32){
      const int row = tid>>1, hw = tid&1;
      const f32x4 v = *(const f32x4*)(hstage + row*16 + hw*8);
      unsigned short* dst = hbuf + (((size_t)(dir*2+(tt&1))*64 + b0 + row)<<9) + us*16 + hw*8;
      asm volatile("global_store_dwordx4 %0, %1, off sc0 sc1" :: "v"(dst), "v"(v) : "memory");
    } else if (tid < 64){
      const int j = tid-32, row = j>>1, hw = j&1;
      const f32x4 v = *(const f32x4*)(estage + row*16 + hw*8);
      *(f32x4*)((unsigned short*)enc + ((size_t)((b0+row)*512 + t))*1024 + dir*512 + us*16 + hw*8) = v;
    }
    asm volatile("s_waitcnt vmcnt(0)" ::: "memory");
    __syncthreads();
    if (tid==0) __hip_atomic_fetch_add(gcnt, 1u, __ATOMIC_RELAXED, AGENT);
  }

  if (tid < 256){
    hfin[dir*32768 + bg*512 + ug] = hprev;
    (dir ? cb : cf)[bg*512 + ug] = creg;
  }
}

// ---------------- decoder init ----------------
__global__ void __launch_bounds__(256) fc_init(
  const float* __restrict__ hf0, const float* __restrict__ hb0,
  const float* __restrict__ cf, const float* __restrict__ cb,
  const float* __restrict__ fchW, const float* __restrict__ fchB,
  const float* __restrict__ fccW, const float* __restrict__ fccB,
  float* __restrict__ dech, float* __restrict__ decc)
{
  const int which = blockIdx.x >> 7;
  const int wid = blockIdx.x & 127;
  const int b = threadIdx.x >> 2, ul = threadIdx.x & 3;
  const int u = wid*4 + ul;
  const float* s0 = which ? cf : hf0;
  const float* s1 = which ? cb : hb0;
  const float* W = which ? fccW : fchW;
  float acc = (which ? fccB : fchB)[u];
  const float4* x0 = (const float4*)(s0 + b*512);
  const float4* x1 = (const float4*)(s1 + b*512);
  const float4* wr = (const float4*)(W + (size_t)u*1024);
  #pragma unroll 4
  for (int k=0;k<128;k++) acc += dot4(x0[k], wr[k]);
  #pragma unroll 4
  for (int k=0;k<128;k++) acc += dot4(x1[k], wr[128+k]);
  (which ? decc : dech)[b*512+u] = tanhfast(acc);
}

// ---------------- eh2 via MFMA ----------------
__global__ void __launch_bounds__(256) eh_mfma(
  const unsigned short* __restrict__ enc,
  const unsigned short* __restrict__ Wencb,
  unsigned short* __restrict__ eh2)
{
  const int b = blockIdx.x>>6, st = (blockIdx.x>>3)&7, nt0 = blockIdx.x&7;
  const int wv = threadIdx.x>>6, lane = threadIdx.x&63;
  const int sA = st*64 + wv*16 + (lane&15);
  const int kb = (lane>>4)*8;
  const unsigned short* ap  = enc + ((size_t)(b*512 + sA))*1024 + kb;
  const unsigned short* bp0 = Wencb + ((size_t)(nt0*64 + (lane&15)))*1024 + kb;
  f32x4 acc[4] = {{0,0,0,0},{0,0,0,0},{0,0,0,0},{0,0,0,0}};
  for (int k0=0; k0<1024; k0+=32){
    V16 a; a.f = *(const f32x4*)(ap + k0);
    #pragma unroll
    for (int nt=0; nt<4; ++nt){
      V16 bb; bb.f = *(const f32x4*)(bp0 + (size_t)nt*16*1024 + k0);
      acc[nt] = __builtin_amdgcn_mfma_f32_16x16x32_bf16(a.s, bb.s, acc[nt], 0, 0, 0);
    }
  }
  const int sO = st*64 + wv*16 + (lane>>4)*4;
  const int col = lane&15;
  #pragma unroll
  for (int nt=0; nt<4; ++nt){
    #pragma unroll
    for (int i=0;i<4;i++){
      eh2[((size_t)(b*512 + sO + i))*512 + nt0*64 + nt*16 + col] = bfbits(acc[nt][i]);
    }
  }
}

// ---------------- encT2[b][j][s] ----------------
__global__ void __launch_bounds__(256) enc_tr(
  const unsigned short* __restrict__ enc, unsigned short* __restrict__ encT2)
{
  __shared__ unsigned short tl[64][80];
  const int b = blockIdx.x>>7, st = (blockIdx.x>>4)&7, jt = blockIdx.x&15;
  const int r = threadIdx.x>>2, q = threadIdx.x&3;
  const unsigned short* src = enc + ((size_t)(b*512 + st*64 + r))*1024 + jt*64 + q*16;
  *(short8*)&tl[r][q*16]   = *(const short8*)src;
  *(short8*)&tl[r][q*16+8] = *(const short8*)(src+8);
  __syncthreads();
  unsigned short tmp[16];
  #pragma unroll
  for (int e=0;e<16;e++) tmp[e] = tl[q*16+e][r];
  unsigned short* dst = encT2 + ((size_t)(b*1024 + jt*64 + r))*512 + st*64 + q*16;
  *(short8*)dst     = *(short8*)&tmp[0];
  *(short8*)(dst+8) = *(short8*)&tmp[8];
}

// ---------------- barriers ----------------
template<int NG>
__device__ __forceinline__ void gbar(unsigned* gctr, unsigned* root, int grp, unsigned gen){
  asm volatile("s_waitcnt vmcnt(0)" ::: "memory");
  __syncthreads();
  if (threadIdx.x==0){
    const unsigned old = __hip_atomic_fetch_add(gctr + grp*32, 1u, __ATOMIC_RELAXED, AGENT);
    if (old == gen*16u - 1u)
      __hip_atomic_fetch_add(root, 1u, __ATOMIC_RELAXED, AGENT);
    while (__hip_atomic_load(root, __ATOMIC_RELAXED, AGENT) < gen*(unsigned)NG)
      __builtin_amdgcn_s_sleep(1);
  }
  __syncthreads();
}
template<int NB>
__device__ __forceinline__ void mbar(unsigned* mc, unsigned mgen){
  asm volatile("s_waitcnt vmcnt(0)" ::: "memory");
  __syncthreads();
  if (threadIdx.x==0){
    __hip_atomic_fetch_add(mc, 1u, __ATOMIC_RELAXED, AGENT);
    while (__hip_atomic_load(mc, __ATOMIC_RELAXED, AGENT) < mgen*(unsigned)NB)
      __builtin_amdgcn_s_sleep(1);
  }
  __syncthreads();
}

// ---------------- dec256 fallback (round-9 proven structure) ----------------
__global__ void __launch_bounds__(512) dec_fused256(
  const float* __restrict__ trg, const int* __restrict__ smask,
  const float* __restrict__ attnv,
  const unsigned short* __restrict__ eh2,
  const unsigned short* __restrict__ encT2,
  const unsigned short* __restrict__ Wcat,
  const unsigned short* __restrict__ Wdecb,
  const float* __restrict__ PQd, const float* __restrict__ hc,
  const float* __restrict__ valW, const float* __restrict__ stopW,
  const float* __restrict__ dech0, const float* __restrict__ decc0,
  float* __restrict__ scorep, float* __restrict__ ctxf,
  unsigned short* __restrict__ xbuf, float* __restrict__ gates,
  float* __restrict__ hcur, float* __restrict__ out,
  unsigned* __restrict__ gctr, unsigned* __restrict__ root, unsigned* __restrict__ mctr)
{
  __shared__ alignas(16) float redl[8192];
  __shared__ float vlds[512];
  __shared__ float hldsa[512];
  __shared__ float adhl[128];
  __shared__ float wlds[512];
  const int tid = threadIdx.x;
  const int bid = blockIdx.x;
  const int b = bid>>2, quad = bid&3;
  const int grp = bid>>4;
  const int lane = tid&63, wv = tid>>6;
  unsigned* mc = mctr + b*32;
  unsigned g = 0, m = 0;

  vlds[tid] = attnv[tid];

  short8 gw[6];
  if (bid < 128){
    const int n = bid*16 + (lane&15);
    const unsigned short* wp = Wcat + (size_t)n*1536 + wv*192 + (lane>>4)*8;
    #pragma unroll
    for (int ks=0;ks<6;ks++) gw[ks] = *(const short8*)(wp + ks*32);
  }

  const bool isb = (quad==0);
  float hr=0.f, cr=0.f;
  float pqi=0,pqf=0,pqg=0,pqo=0, qqi=0,qqf=0,qqg=0,qqo=0;
  float vwh=0,vwc0=0,vwc1=0, swh=0,swc0=0,swc1=0;
  if (isb){
    hr = dech0[b*512+tid]; cr = decc0[b*512+tid];
    pqi = PQd[tid];      pqf = PQd[512+tid];      pqg = PQd[1024+tid];      pqo = PQd[1536+tid];
    qqi = PQd[2048+tid]; qqf = PQd[2048+512+tid]; qqg = PQd[2048+1024+tid]; qqo = PQd[2048+1536+tid];
    vwh = valW[tid]; vwc0 = valW[512+tid]; vwc1 = valW[1024+tid];
    swh = stopW[tid]; swc0 = stopW[512+tid]; swc1 = stopW[1024+tid];
  }

  if (isb){
    const unsigned hb16 = (unsigned)bfbits(hr);
    unsigned short* xp = xbuf + b*1536 + 1024 + tid;
    asm volatile("global_store_short %0, %1, off sc0 sc1" :: "v"(xp), "v"(hb16) : "memory");
    float* hp = hcur + b*512 + tid;
    asm volatile("global_store_dword %0, %1, off sc0 sc1" :: "v"(hp), "v"(hr) : "memory");
  }
  ++m; mbar<4>(mc, m);

  for (int t=0; t<95; ++t){
    {
      float hv; const float* hp = hcur + b*512 + tid;
      asm volatile("global_load_dword %0, %1, off sc0 sc1\ns_waitcnt vmcnt(0)" : "=v"(hv) : "v"(hp) : "memory");
      hldsa[tid] = hv;
      __syncthreads();
      {
        const int jl = tid>>2, uc = tid&3;
        const unsigned short* wp = Wdecb + (size_t)(quad*128 + jl)*512 + uc*128;
        float a = 0.f;
        #pragma unroll
        for (int i=0;i<16;i++){
          const short8 w8 = *(const short8*)(wp + i*8);
          #pragma unroll
          for (int e=0;e<8;e++)
            a = fmaf(hldsa[uc*128 + i*8 + e], bfu2f((unsigned short)w8[e]), a);
        }
        redl[tid] = a;
      }
      __syncthreads();
      if (tid < 128)
        adhl[tid] = redl[tid*4] + redl[tid*4+1] + redl[tid*4+2] + redl[tid*4+3];
      __syncthreads();
      {
        const unsigned short* ep = eh2 + ((size_t)(b*512 + tid))*512 + quad*128;
        float part = 0.f;
        #pragma unroll
        for (int i=0;i<16;i++){
          const short8 e8 = *(const short8*)(ep + i*8);
          #pragma unroll
          for (int e=0;e<8;e++){
            const int n = i*8 + e;
            part = fmaf(vlds[quad*128+n], tanhfast(adhl[n] + bfu2f((unsigned short)e8[e])), part);
          }
        }
        float* sp = scorep + (size_t)bid*512 + tid;
        asm volatile("global_store_dword %0, %1, off sc0 sc1" :: "v"(sp), "v"(part) : "memory");
      }
    }
    ++m; mbar<4>(mc, m);

    {
      float pa, pb, pc, pd;
      const float* pp = scorep + (size_t)(b*4)*512 + tid;
      asm volatile("global_load_dword %0, %1, off sc0 sc1" : "=v"(pa) : "v"(pp) : "memory");
      asm volatile("global_load_dword %0, %1, off sc0 sc1" : "=v"(pb) : "v"(pp+512) : "memory");
      asm volatile("global_load_dword %0, %1, off sc0 sc1" : "=v"(pc) : "v"(pp+1024) : "memory");
      asm volatile("global_load_dword %0, %1, off sc0 sc1" : "=v"(pd) : "v"(pp+1536) : "memory");
      asm volatile("s_waitcnt vmcnt(0)" ::: "memory");
      __builtin_amdgcn_sched_barrier(0);
      float s0 = (pa+pb)+(pc+pd);
      s0 = smask[b*512+tid] ? s0 : -1.0e9f;
      redl[512+tid] = s0;
      __syncthreads();
      for (int off=256; off>0; off>>=1){
        if (tid<off) redl[512+tid] = fmaxf(redl[512+tid], redl[512+tid+off]);
        __syncthreads();
      }
      const float mx = redl[512];
      __syncthreads();
      const float e = __expf(s0 - mx);
      redl[512+tid] = e;
      __syncthreads();
      for (int off=256; off>0; off>>=1){
        if (tid<off) redl[512+tid] += redl[512+tid+off];
        __syncthreads();
      }
      const float Z = redl[512];
      __syncthreads();
      wlds[tid] = e / Z;
      __syncthreads();
      {
        const int jj = tid>>1, sh = tid&1;
        const unsigned short* cp = encT2 + ((size_t)(b*1024 + quad*256 + jj))*512 + sh*256;
        float c = 0.f;
        #pragma unroll
        for (int i=0;i<32;i++){
          const short8 c8 = *(const short8*)(cp + i*8);
          #pragma unroll
          for (int e2=0;e2<8;e2++)
            c = fmaf(wlds[sh*256 + i*8 + e2], bfu2f((unsigned short)c8[e2]), c);
        }
        redl[tid] = c;
      }
      __syncthreads();
      if (tid < 256){
        const float cv = redl[tid*2] + redl[tid*2+1];
        const int j = quad*256 + tid;
        float* cp2 = ctxf + b*1024 + j;
        asm volatile("global_store_dword %0, %1, off sc0 sc1" :: "v"(cp2), "v"(cv) : "memory");
        const unsigned cb16 = (unsigned)bfbits(cv);
        unsigned short* xp = xbuf + b*1536 + j;
        asm volatile("global_store_short %0, %1, off sc0 sc1" :: "v"(xp), "v"(cb16) : "memory");
      }
    }
    ++g; gbar<16>(gctr, root, grp, g);

    if (bid < 128){
      f32x4 av[2][6];
      f32x4 acc[4] = {{0,0,0,0},{0,0,0,0},{0,0,0,0},{0,0,0,0}};
      {
        const unsigned short* xp0 = xbuf + (size_t)(lane&15)*1536 + wv*192 + (lane>>4)*8;
        #pragma unroll
        for (int ks=0;ks<6;ks++){
          const unsigned short* p = xp0 + ks*32;
          asm volatile("global_load_dwordx4 %0, %1, off sc0 sc1" : "=v"(av[0][ks]) : "v"(p) : "memory");
        }
      }
      #pragma unroll
      for (int mt=0; mt<4; ++mt){
        if (mt<3){
          const unsigned short* xpn = xbuf + (size_t)((mt+1)*16 + (lane&15))*1536 + wv*192 + (lane>>4)*8;
          #pragma unroll
          for (int ks=0;ks<6;ks++){
            const unsigned short* p = xpn + ks*32;
            asm volatile("global_load_dwordx4 %0, %1, off sc0 sc1" : "=v"(av[(mt+1)&1][ks]) : "v"(p) : "memory");
          }
          asm volatile("s_waitcnt vmcnt(6)" ::: "memory");
        } else {
          asm volatile("s_waitcnt vmcnt(0)" ::: "memory");
        }
        __builtin_amdgcn_sched_barrier(0);
        #pragma unroll
        for (int ks=0;ks<6;ks++){
          V16 a; a.f = av[mt&1][ks];
          acc[mt] = __builtin_amdgcn_mfma_f32_16x16x32_bf16(a.s, gw[ks], acc[mt], 0, 0, 0);
        }
      }
      #pragma unroll
      for (int mt=0; mt<4; ++mt)
        *(f32x4*)&redl[wv*1024 + lane*16 + mt*4] = acc[mt];
    }
    __syncthreads();
    if (bid < 128){
      #pragma unroll
      for (int h2=0; h2<2; ++h2){
        const int o = h2*512 + tid;
        const int ob = o>>4, col = o&15;
        const int mt = ob>>4, row = ob&15;
        const int base = (((row>>2)<<4) | col)*16 + mt*4 + (row&3);
        float gsum = 0.f;
        #pragma unroll
        for (int w2=0; w2<8; ++w2) gsum += redl[w2*1024 + base];
        float* gp = gates + ob*2048 + bid*16 + col;
        asm volatile("global_store_dword %0, %1, off sc0 sc1" :: "v"(gp), "v"(gsum) : "memory");
      }
    }
    ++g; gbar<16>(gctr, root, grp, g);

    if (isb){
      float g4[4], c0v, c1v;
      {
        const float* gp = gates + b*2048 + tid;
        const float* cp = ctxf + b*1024 + tid;
        asm volatile("global_load_dword %0, %1, off sc0 sc1" : "=v"(g4[0]) : "v"(gp) : "memory");
        asm volatile("global_load_dword %0, %1, off sc0 sc1" : "=v"(g4[1]) : "v"(gp+512) : "memory");
        asm volatile("global_load_dword %0, %1, off sc0 sc1" : "=v"(g4[2]) : "v"(gp+1024) : "memory");
        asm volatile("global_load_dword %0, %1, off sc0 sc1" : "=v"(g4[3]) : "v"(gp+1536) : "memory");
        asm volatile("global_load_dword %0, %1, off sc0 sc1" : "=v"(c0v) : "v"(cp) : "memory");
        asm volatile("global_load_dword %0, %1, off sc0 sc1" : "=v"(c1v) : "v"(cp+512) : "memory");
        asm volatile("s_waitcnt vmcnt(0)" ::: "memory");
        __builtin_amdgcn_sched_barrier(0);
      }
      const float x = trg[b*96 + t]*0.001f;
      const float gi = g4[0] + x*pqi + qqi;
      const float gf = g4[1] + x*pqf + qqf;
      const float gg = g4[2] + x*pqg + qqg;
      const float go = g4[3] + x*pqo + qqo;
      const float cn = fmaf(sigm(gf), cr, sigm(gi)*tanhfast(gg));
      const float hn = sigm(go)*tanhfast(cn);
      cr = cn; hr = hn;
      const unsigned hb16 = (unsigned)bfbits(hn);
      unsigned short* xp = xbuf + b*1536 + 1024 + tid;
      asm volatile("global_store_short %0, %1, off sc0 sc1" :: "v"(xp), "v"(hb16) : "memory");
      float* hp = hcur + b*512 + tid;
      asm volatile("global_store_dword %0, %1, off sc0 sc1" :: "v"(hp), "v"(hn) : "memory");
      redl[512+tid]  = fmaf(hn, vwh, fmaf(c0v, vwc0, c1v*vwc1));
      redl[1024+tid] = fmaf(hn, swh, fmaf(c0v, swc0, c1v*swc1));
      __syncthreads();
      for (int off=256; off>0; off>>=1){
        if (tid<off){ redl[512+tid]+=redl[512+tid+off]; redl[1024+tid]+=redl[1024+tid+off]; }
        __syncthreads();
      }
      if (tid==0){
        out[b*95 + t] = (redl[512] + x*hc[0] + hc[1])*1000.f;
        out[6080 + b*95 + t] = redl[1024] + x*hc[2] + hc[3];
      }
    }
    ++m; mbar<4>(mc, m);
  }
}

// ---------------- dec512 v2: eh2-in-LDS + len-skip + prefetch ----------------
__global__ void __launch_bounds__(512, 4) dec_fused512(
  const float* __restrict__ trg, const int* __restrict__ smask,
  const float* __restrict__ attnv,
  const unsigned short* __restrict__ eh2,    // [64][512 s][512 n]
  const unsigned short* __restrict__ encT2,  // [64][1024 j][512 s]
  const unsigned short* __restrict__ Wcat,
  const unsigned short* __restrict__ Wdecb,  // [512 j][512 u]
  const float* __restrict__ PQd, const float* __restrict__ hc,
  const float* __restrict__ valW, const float* __restrict__ stopW,
  const float* __restrict__ dech0, const float* __restrict__ decc0,
  float* __restrict__ scorep, float* __restrict__ ctxf,
  unsigned short* __restrict__ xbuf, float* __restrict__ gates,
  float* __restrict__ hcur, float* __restrict__ out,
  unsigned* __restrict__ gctr, unsigned* __restrict__ root, unsigned* __restrict__ mctr)
{
  __shared__ unsigned short eh2l[32768];      // [n 64][s 512] n-major, 64 KB
  __shared__ alignas(16) float redl[2048];    // phase-shared scratch (8 KB)
  __shared__ float vlds[512];
  __shared__ float adhl[64];
  __shared__ int slen_sh;
  const int tid = threadIdx.x;
  const int bid = blockIdx.x;
  const int b = bid>>3, oct = bid&7;
  const int grp = bid>>4;
  const int lane = tid&63, wv = tid>>6;
  unsigned* mc = mctr + b*32;
  unsigned g = 0, m = 0;

  vlds[tid] = attnv[tid];

  // one-time: per-b valid length (smask is prefix-form)
  redl[tid] = (float)smask[b*512+tid];
  __syncthreads();
  for (int off=256; off>0; off>>=1){
    if (tid<off) redl[tid] += redl[tid+off];
    __syncthreads();
  }
  if (tid==0) slen_sh = (int)(redl[0]+0.5f);
  __syncthreads();
  const int slen = slen_sh;
  const int nch = (slen + 127) >> 7;

  // one-time: fill eh2l (transpose row s=tid into n-major)
  {
    const unsigned short* ep = eh2 + ((size_t)(b*512 + tid))*512 + oct*64;
    short8 r8[8];
    #pragma unroll
    for (int i=0;i<8;i++) r8[i] = *(const short8*)(ep + i*8);
    #pragma unroll
    for (int i=0;i<8;i++)
      #pragma unroll
      for (int e=0;e<8;e++)
        eh2l[(i*8+e)*512 + tid] = (unsigned short)r8[i][e];
  }
  __syncthreads();

  short8 gw[6];
  if (bid < 128){
    const int n = bid*16 + (lane&15);
    const unsigned short* wp = Wcat + (size_t)n*1536 + wv*192 + (lane>>4)*8;
    #pragma unroll
    for (int ks=0;ks<6;ks++) gw[ks] = *(const short8*)(wp + ks*32);
  }

  const bool isb = (oct==0);
  float hr=0.f, cr=0.f;
  float pqi=0,pqf=0,pqg=0,pqo=0, qqi=0,qqf=0,qqg=0,qqo=0;
  float vwh=0,vwc0=0,vwc1=0, swh=0,swc0=0,swc1=0;
  if (isb){
    hr = dech0[b*512+tid]; cr = decc0[b*512+tid];
    pqi = PQd[tid];      pqf = PQd[512+tid];      pqg = PQd[1024+tid];      pqo = PQd[1536+tid];
    qqi = PQd[2048+tid]; qqf = PQd[2048+512+tid]; qqg = PQd[2048+1024+tid]; qqo = PQd[2048+1536+tid];
    vwh = valW[tid]; vwc0 = valW[512+tid]; vwc1 = valW[1024+tid];
    swh = stopW[tid]; swc0 = stopW[512+tid]; swc1 = stopW[1024+tid];
  }

  if (isb){
    const unsigned hb16 = (unsigned)bfbits(hr);
    unsigned short* xp = xbuf + b*1536 + 1024 + tid;
    asm volatile("global_store_short %0, %1, off sc0 sc1" :: "v"(xp), "v"(hb16) : "memory");
    float* hp = hcur + b*512 + tid;
    asm volatile("global_store_dword %0, %1, off sc0 sc1" :: "v"(hp), "v"(hr) : "memory");
  }
  ++m; mbar<8>(mc, m);

  for (int t=0; t<95; ++t){
    // ---- ADH + score (eh2 from LDS) ----
    {
      float hv; const float* hp = hcur + b*512 + tid;
      asm volatile("global_load_dword %0, %1, off sc0 sc1\ns_waitcnt vmcnt(0)" : "=v"(hv) : "v"(hp) : "memory");
      redl[1024+tid] = hv;     // h in LDS
      __syncthreads();
      {
        const int jl = tid>>3, uc = tid&7;
        const unsigned short* wp = Wdecb + (size_t)(oct*64 + jl)*512 + uc*64;
        float a = 0.f;
        #pragma unroll
        for (int i=0;i<8;i++){
          const short8 w8 = *(const short8*)(wp + i*8);
          #pragma unroll
          for (int e=0;e<8;e++)
            a = fmaf(redl[1024 + uc*64 + i*8 + e], bfu2f((unsigned short)w8[e]), a);
        }
        redl[tid] = a;
      }
      __syncthreads();
      if (tid < 64){
        float s8 = 0.f;
        #pragma unroll
        for (int i=0;i<8;i++) s8 += redl[tid*8+i];
        adhl[tid] = s8;
      }
      __syncthreads();
      {
        float part = 0.f;
        #pragma unroll 8
        for (int n=0;n<64;++n)
          part = fmaf(vlds[oct*64+n], tanhfast(adhl[n] + bfu2f(eh2l[n*512 + tid])), part);
        float* sp = scorep + (size_t)bid*512 + tid;
        asm volatile("global_store_dword %0, %1, off sc0 sc1" :: "v"(sp), "v"(part) : "memory");
      }
    }
    ++m; mbar<8>(mc, m);

    // ---- P2b: softmax + ctx chunk (len-skip + prefetch) ----
    {
      // 1) issue scorep partial loads (sc0)
      float ps[8];
      const float* pp = scorep + (size_t)(b*8)*512 + tid;
      #pragma unroll
      for (int i=0;i<8;i++){
        const float* p = pp + i*512;
        asm volatile("global_load_dword %0, %1, off sc0 sc1" : "=v"(ps[i]) : "v"(p) : "memory");
      }
      // 2) issue first-half encT2 prefetch (cached); inactive lanes clamp to chunk 0
      const int jj = tid>>2, sh = tid&3;
      const bool act = (sh < nch);
      const int she = act ? sh : 0;
      const unsigned short* cp = encT2 + ((size_t)(b*1024 + oct*128 + jj))*512 + she*128;
      f32x4 pre[8];
      #pragma unroll
      for (int i=0;i<8;i++){
        const unsigned short* p = cp + i*8;
        asm volatile("global_load_dwordx4 %0, %1, off" : "=v"(pre[i]) : "v"(p) : "memory");
      }
      // 3) wait only for partials (they are the 8 oldest)
      asm volatile("s_waitcnt vmcnt(8)" ::: "memory");
      __builtin_amdgcn_sched_barrier(0);
      float s0 = ((ps[0]+ps[1])+(ps[2]+ps[3]))+((ps[4]+ps[5])+(ps[6]+ps[7]));
      s0 = (tid < slen) ? s0 : -1.0e9f;
      // 4) softmax (pure LDS/VALU — prefetch drains underneath)
      redl[512+tid] = s0;
      __syncthreads();
      for (int off=256; off>0; off>>=1){
        if (tid<off) redl[512+tid] = fmaxf(redl[512+tid], redl[512+tid+off]);
        __syncthreads();
      }
      const float mx = redl[512];
      __syncthreads();
      const float e = __expf(s0 - mx);
      redl[512+tid] = e;
      __syncthreads();
      for (int off=256; off>0; off>>=1){
        if (tid<off) redl[512+tid] += redl[512+tid+off];
        __syncthreads();
      }
      const float Z = redl[512];
      __syncthreads();
      redl[1024+tid] = e / Z;        // w
      __syncthreads();
      // 5) consume prefetched half + stream second half
      float c = 0.f;
      asm volatile("s_waitcnt vmcnt(0)" ::: "memory");
      __builtin_amdgcn_sched_barrier(0);
      #pragma unroll
      for (int i=0;i<8;i++){
        V16 x; x.f = pre[i];
        #pragma unroll
        for (int e2=0;e2<8;e2++)
          c = fmaf(redl[1024 + she*128 + i*8 + e2], bfu2f((unsigned short)x.s[e2]), c);
      }
      #pragma unroll
      for (int i=8;i<16;i++){
        const short8 c8 = *(const short8*)(cp + i*8);
        #pragma unroll
        for (int e2=0;e2<8;e2++)
          c = fmaf(redl[1024 + she*128 + i*8 + e2], bfu2f((unsigned short)c8[e2]), c);
      }
      c = act ? c : 0.f;
      redl[tid] = c;
      __syncthreads();
      if (tid < 128){
        const float cv = redl[tid*4] + redl[tid*4+1] + redl[tid*4+2] + redl[tid*4+3];
        const int j = oct*128 + tid;
        float* cp2 = ctxf + b*1024 + j;
        asm volatile("global_store_dword %0, %1, off sc0 sc1" :: "v"(cp2), "v"(cv) : "memory");
        const unsigned cb16 = (unsigned)bfbits(cv);
        unsigned short* xp = xbuf + b*1536 + j;
        asm volatile("global_store_short %0, %1, off sc0 sc1" :: "v"(xp), "v"(cb16) : "memory");
      }
    }
    ++g; gbar<32>(gctr, root, grp, g);

    // ---- P4: gates MFMA (bid<128), LDS-atomicAdd k-reduction ----
    redl[tid] = 0.f; redl[512+tid] = 0.f;
    __syncthreads();
    if (bid < 128){
      f32x4 av[2][6];
      f32x4 acc[4] = {{0,0,0,0},{0,0,0,0},{0,0,0,0},{0,0,0,0}};
      {
        const unsigned short* xp0 = xbuf + (size_t)(lane&15)*1536 + wv*192 + (lane>>4)*8;
        #pragma unroll
        for (int ks=0;ks<6;ks++){
          const unsigned short* p = xp0 + ks*32;
          asm volatile("global_load_dwordx4 %0, %1, off sc0 sc1" : "=v"(av[0][ks]) : "v"(p) : "memory");
        }
      }
      #pragma unroll
      for (int mt=0; mt<4; ++mt){
        if (mt<3){
          const unsigned short* xpn = xbuf + (size_t)((mt+1)*16 + (lane&15))*1536 + wv*192 + (lane>>4)*8;
          #pragma unroll
          for (int ks=0;ks<6;ks++){
            const unsigned short* p = xpn + ks*32;
            asm volatile("global_load_dwordx4 %0, %1, off sc0 sc1" : "=v"(av[(mt+1)&1][ks]) : "v"(p) : "memory");
          }
          asm volatile("s_waitcnt vmcnt(6)" ::: "memory");
        } else {
          asm volatile("s_waitcnt vmcnt(0)" ::: "memory");
        }
        __builtin_amdgcn_sched_barrier(0);
        #pragma unroll
        for (int ks=0;ks<6;ks++){
          V16 a; a.f = av[mt&1][ks];
          acc[mt] = __builtin_amdgcn_mfma_f32_16x16x32_bf16(a.s, gw[ks], acc[mt], 0, 0, 0);
        }
      }
      #pragma unroll
      for (int mt=0; mt<4; ++mt)
        #pragma unroll
        for (int i=0;i<4;i++){
          const int r = (lane>>4)*4 + i, cc = lane&15;
          atomicAdd(&redl[(mt*16 + r)*16 + cc], acc[mt][i]);
        }
    }
    __syncthreads();
    if (bid < 128){
      #pragma unroll
      for (int h2=0; h2<2; ++h2){
        const int o = h2*512 + tid;
        const int ob = o>>4, col = o&15;
        const float gsum = redl[o];
        float* gp = gates + ob*2048 + bid*16 + col;
        asm volatile("global_store_dword %0, %1, off sc0 sc1" :: "v"(gp), "v"(gsum) : "memory");
      }
    }
    ++g; gbar<32>(gctr, root, grp, g);

    // ---- P5: cell update + heads (oct==0) ----
    if (isb){
      float g4[4], c0v, c1v;
      {
        const float* gp = gates + b*2048 + tid;
        const float* cp = ctxf + b*1024 + tid;
        asm volatile("global_load_dword %0, %1, off sc0 sc1" : "=v"(g4[0]) : "v"(gp) : "memory");
        asm volatile("global_load_dword %0, %1, off sc0 sc1" : "=v"(g4[1]) : "v"(gp+512) : "memory");
        asm volatile("global_load_dword %0, %1, off sc0 sc1" : "=v"(g4[2]) : "v"(gp+1024) : "memory");
        asm volatile("global_load_dword %0, %1, off sc0 sc1" : "=v"(g4[3]) : "v"(gp+1536) : "memory");
        asm volatile("global_load_dword %0, %1, off sc0 sc1" : "=v"(c0v) : "v"(cp) : "memory");
        asm volatile("global_load_dword %0, %1, off sc0 sc1" : "=v"(c1v) : "v"(cp+512) : "memory");
        asm volatile("s_waitcnt vmcnt(0)" ::: "memory");
        __builtin_amdgcn_sched_barrier(0);
      }
      const float x = trg[b*96 + t]*0.001f;
      const float gi = g4[0] + x*pqi + qqi;
      const float gf = g4[1] + x*pqf + qqf;
      const float gg = g4[2] + x*pqg + qqg;
      const float go = g4[3] + x*pqo + qqo;
      const float cn = fmaf(sigm(gf), cr, sigm(gi)*tanhfast(gg));
      const float hn = sigm(go)*tanhfast(cn);
      cr = cn; hr = hn;
      const unsigned hb16 = (unsigned)bfbits(hn);
      unsigned short* xp = xbuf + b*1536 + 1024 + tid;
      asm volatile("global_store_short %0, %1, off sc0 sc1" :: "v"(xp), "v"(hb16) : "memory");
      float* hp = hcur + b*512 + tid;
      asm volatile("global_store_dword %0, %1, off sc0 sc1" :: "v"(hp), "v"(hn) : "memory");
      redl[512+tid]  = fmaf(hn, vwh, fmaf(c0v, vwc0, c1v*vwc1));
      redl[1024+tid] = fmaf(hn, swh, fmaf(c0v, swc0, c1v*swc1));
      __syncthreads();
      for (int off=256; off>0; off>>=1){
        if (tid<off){ redl[512+tid]+=redl[512+tid+off]; redl[1024+tid]+=redl[1024+tid+off]; }
        __syncthreads();
      }
      if (tid==0){
        out[b*95 + t] = (redl[512] + x*hc[0] + hc[1])*1000.f;
        out[6080 + b*95 + t] = redl[1024] + x*hc[2] + hc[3];
      }
    }
    ++m; mbar<8>(mc, m);
  }
}

// ---------------- launch ----------------
extern "C" void kernel_launch(void* const* d_in, const int* in_sizes, int n_in,
                              void* d_out, int out_size, void* d_ws, size_t ws_size,
                              hipStream_t stream)
{
  (void)in_sizes; (void)n_in; (void)out_size; (void)ws_size;
  const float* src   = (const float*)d_in[0];
  const int*   smask = (const int*)  d_in[1];
  const float* trg   = (const float*)d_in[2];
  const float* epW   = (const float*)d_in[4];
  const float* epb   = (const float*)d_in[5];
  const float* Wihf  = (const float*)d_in[6];
  const float* Whhf  = (const float*)d_in[7];
  const float* bihf  = (const float*)d_in[8];
  const float* bhhf  = (const float*)d_in[9];
  const float* Wihb  = (const float*)d_in[10];
  const float* Whhb  = (const float*)d_in[11];
  const float* bihb  = (const float*)d_in[12];
  const float* bhhb  = (const float*)d_in[13];
  const float* fchW  = (const float*)d_in[14];
  const float* fchB  = (const float*)d_in[15];
  const float* fccW  = (const float*)d_in[16];
  const float* fccB  = (const float*)d_in[17];
  const float* dpW   = (const float*)d_in[18];
  const float* dpb   = (const float*)d_in[19];
  const float* Wenc  = (const float*)d_in[20];
  const float* Wdec  = (const float*)d_in[21];
  const float* attnv = (const float*)d_in[22];
  const float* dWih  = (const float*)d_in[23];
  const float* dWhh  = (const float*)d_in[24];
  const float* dbih  = (const float*)d_in[25];
  const float* dbhh  = (const float*)d_in[26];
  const float* valW  = (const float*)d_in[27];
  const float* valb  = (const float*)d_in[28];
  const float* stopW = (const float*)d_in[29];
  const float* stopb = (const float*)d_in[30];
  float* out = (float*)d_out;

  // ---- bump allocator ----
  char* ws = (char*)d_ws;
  size_t off = 0;
  auto take = [&](size_t nbytes) -> char* {
    char* p = ws + off;
    off += (nbytes + 255) & ~(size_t)255;
    return p;
  };
  unsigned short* enc   = (unsigned short*)take((size_t)64*512*1024*2);
  unsigned short* eh2   = (unsigned short*)take((size_t)64*512*512*2);
  unsigned short* encT2 = (unsigned short*)take((size_t)64*1024*512*2);
  unsigned short* hbuf  = (unsigned short*)take(2*2*64*512*2);
  unsigned short* Wbf   = (unsigned short*)take((size_t)2*2048*512*2);
  unsigned short* Wcat  = (unsigned short*)take((size_t)2048*1536*2);
  unsigned short* Wdecb = (unsigned short*)take(512*512*2);
  unsigned short* Wencb = (unsigned short*)take(512*1024*2);
  float* WT    = (float*)take((size_t)1024*512*4);
  float* hfin  = (float*)take(2*64*512*4);
  float* cf    = (float*)take(64*512*4);
  float* cb    = (float*)take(64*512*4);
  float* PQ    = (float*)take(6*2048*4);
  float* dech0 = (float*)take(64*512*4);
  float* decc0 = (float*)take(64*512*4);
  float* scorep= (float*)take(512*512*4);
  float* ctxf  = (float*)take(64*1024*4);
  unsigned short* xbuf = (unsigned short*)take(64*1536*2);
  float* gates = (float*)take(64*2048*4);
  float* hcur  = (float*)take(64*512*4);
  float* hc    = (float*)take(256);
  unsigned* cnt  = (unsigned*)take(1024);
  unsigned* gctr = (unsigned*)take(4096);
  unsigned* root = (unsigned*)take(256);
  unsigned* mctr = (unsigned*)take(8192);
  float* PQd = PQ + 8192;
  (void)hipMemsetAsync(cnt, 0, 1024+4096+256+8192, stream);

  precompute<<<2097, 256, 0, stream>>>(Wenc, Wihf, epW, epb, bihf, bhhf, Wihb, bihb, bhhb,
                                       dWih, dpW, dpb, dbih, dbhh, valW, valb, stopW, stopb,
                                       PQ, WT, hc);
  wconv<<<11776, 512, 0, stream>>>(Whhf, Whhb, dWih, dWhh, Wdec, Wenc, Wbf, Wcat, Wdecb, Wencb);

  {
    void* args[] = { (void*)&src, (void*)&smask, (void*)&Wbf, (void*)&PQ,
                     (void*)&hbuf, (void*)&hfin, (void*)&cf, (void*)&cb, (void*)&enc, (void*)&cnt };
    (void)hipLaunchCooperativeKernel((void*)enc_mfma, dim3(256), dim3(512), args, 0, stream);
  }

  {
    const float* hfF = hfin;
    const float* hbF = hfin + 32768;
    fc_init<<<256, 256, 0, stream>>>(hfF, hbF, cf, cb, fchW, fchB, fccW, fccB, dech0, decc0);
  }
  eh_mfma<<<4096, 256, 0, stream>>>(enc, Wencb, eh2);
  enc_tr<<<8192, 256, 0, stream>>>(enc, encT2);

  {
    void* args[] = { (void*)&trg, (void*)&smask, (void*)&attnv,
                     (void*)&eh2, (void*)&encT2, (void*)&Wcat, (void*)&Wdecb,
                     (void*)&PQd, (void*)&hc, (void*)&valW, (void*)&stopW,
                     (void*)&dech0, (void*)&decc0,
                     (void*)&scorep, (void*)&ctxf,
                     (void*)&xbuf, (void*)&gates, (void*)&hcur, (void*)&out,
                     (void*)&gctr, (void*)&root, (void*)&mctr };
    int nb2 = 0;
    (void)hipOccupancyMaxActiveBlocksPerMultiprocessor(&nb2, dec_fused512, 512, 0);
    hipError_t e512 = hipErrorUnknown;
    if (nb2 >= 2)
      e512 = hipLaunchCooperativeKernel((void*)dec_fused512, dim3(512), dim3(512), args, 0, stream);
    if (e512 != hipSuccess)
      (void)hipLaunchCooperativeKernel((void*)dec_fused256, dim3(256), dim3(512), args, 0, stream);
  }
}

// Round 13
// 7010.081 us; speedup vs baseline: 1.0119x; 1.0119x over previous
//
#include <hip/hip_runtime.h>
#include <hip/hip_bf16.h>

#define AGENT __HIP_MEMORY_SCOPE_AGENT

typedef float f32x4 __attribute__((ext_vector_type(4)));
typedef short short8 __attribute__((ext_vector_type(8)));
union V16 { f32x4 f; short8 s; };

// B=64 S=512 T=96 E=256 H=512 ENC_DIM=1024 4H=2048

__device__ __forceinline__ float sigm(float x){ return 1.f/(1.f+__expf(-x)); }
__device__ __forceinline__ float tanhfast(float x){
  float ax = fabsf(x);
  float e = __expf(-2.f*ax);
  float r = (1.f-e)/(1.f+e);
  return copysignf(r, x);
}
__device__ __forceinline__ float dot4(float4 a, float4 b){
  return fmaf(a.x,b.x, fmaf(a.y,b.y, fmaf(a.z,b.z, a.w*b.w)));
}
__device__ __forceinline__ unsigned short bfbits(float x){
  return __bfloat16_as_ushort(__float2bfloat16(x));
}
__device__ __forceinline__ float bfu2f(unsigned short u){
  union{unsigned v; float f;} x; x.v = ((unsigned)u)<<16; return x.f;
}

// ---------------- precompute ----------------
__global__ void __launch_bounds__(256) precompute(
  const float* __restrict__ Wenc,
  const float* __restrict__ Wihf, const float* __restrict__ epW, const float* __restrict__ epb,
  const float* __restrict__ bihf, const float* __restrict__ bhhf,
  const float* __restrict__ Wihb, const float* __restrict__ bihb, const float* __restrict__ bhhb,
  const float* __restrict__ dWih, const float* __restrict__ dpW, const float* __restrict__ dpb,
  const float* __restrict__ dbih, const float* __restrict__ dbhh,
  const float* __restrict__ valW, const float* __restrict__ valb,
  const float* __restrict__ stopW, const float* __restrict__ stopb,
  float* __restrict__ PQ, float* __restrict__ WT, float* __restrict__ hc)
{
  const int idx = blockIdx.x*256 + threadIdx.x;
  if (idx < 524288){
    const int j = idx >> 9, n = idx & 511;
    WT[idx] = Wenc[(size_t)n*1024 + j];
  } else if (idx < 524288 + 6*2048){
    const int q = idx - 524288;
    const int set = q >> 11, j = q & 2047;
    const float* row; const float* vec; float add = 0.f;
    switch(set){
      case 0: row = Wihf + (size_t)j*256; vec = epW; break;
      case 1: row = Wihf + (size_t)j*256; vec = epb; add = bihf[j]+bhhf[j]; break;
      case 2: row = Wihb + (size_t)j*256; vec = epW; break;
      case 3: row = Wihb + (size_t)j*256; vec = epb; add = bihb[j]+bhhb[j]; break;
      case 4: row = dWih + (size_t)j*1280; vec = dpW; break;
      default: row = dWih + (size_t)j*1280; vec = dpb; add = dbih[j]+dbhh[j]; break;
    }
    float a = add;
    for (int e=0;e<256;e++) a = fmaf(row[e], vec[e], a);
    PQ[set*2048 + j] = a;
  } else if (idx < 524288 + 6*2048 + 4){
    const int q = idx - (524288 + 6*2048);
    const float* wrow = (q<2) ? valW : stopW;
    const float* vec  = (q&1) ? dpb : dpW;
    float a = (q&1) ? ((q<2)? valb[0] : stopb[0]) : 0.f;
    for (int e=0;e<256;e++) a = fmaf(wrow[1536+e], vec[e], a);
    hc[q] = a;
  }
}

// ---------------- weight converts ----------------
__global__ void __launch_bounds__(512) wconv(
  const float* __restrict__ Whhf, const float* __restrict__ Whhb,
  const float* __restrict__ dWih, const float* __restrict__ dWhh,
  const float* __restrict__ Wdec, const float* __restrict__ Wenc,
  unsigned short* __restrict__ Wbf, unsigned short* __restrict__ Wcat,
  unsigned short* __restrict__ Wdecb, unsigned short* __restrict__ Wencb)
{
  const int i = blockIdx.x*512 + threadIdx.x;
  if (i < 2097152){
    const float v = (i < 1048576) ? Whhf[i] : Whhb[i-1048576];
    Wbf[i] = bfbits(v);
  } else if (i < 2097152+3145728){
    const int q = i - 2097152;
    const int r = q/1536, k = q - r*1536;
    const float v = (k<1024) ? dWih[(size_t)r*1280 + 256 + k] : dWhh[(size_t)r*512 + (k-1024)];
    Wcat[q] = bfbits(v);
  } else if (i < 2097152+3145728+262144){
    const int q = i - (2097152+3145728);
    Wdecb[q] = bfbits(Wdec[q]);   // row-major [j][u]
  } else if (i < 2097152+3145728+262144+524288){
    const int q = i - (2097152+3145728+262144);
    Wencb[q] = bfbits(Wenc[q]);   // row-major [n][k]
  }
}

// ---------------- encoder (unchanged, proven) ----------------
__global__ void __launch_bounds__(512) enc_mfma(
    const float* __restrict__ src, const int* __restrict__ smask,
    const unsigned short* __restrict__ Wbf,
    const float* __restrict__ PQ,
    unsigned short* __restrict__ hbuf,
    float* __restrict__ hfin,
    float* __restrict__ cf, float* __restrict__ cb,
    __hip_bfloat16* __restrict__ enc,
    unsigned* __restrict__ cnt)
{
  __shared__ float hlds[16*256];
  __shared__ float red[4*64*4];
  __shared__ float gbuf[4*256];
  __shared__ alignas(16) unsigned short hstage[256];
  __shared__ alignas(16) unsigned short estage[256];

  const int tid = threadIdx.x;
  const int bid = blockIdx.x;
  const int dir = bid>>7, bhalf = (bid>>5)&3, us = bid&31;
  const int b0 = bhalf*16;
  unsigned* gcnt = cnt + (dir*4 + bhalf)*32;
  const int wv = tid>>6, lane = tid&63;
  const int nt = wv&3, kh = wv>>2;
  const int rowb = lane&15;

  short8 bfr[8];
  {
    const int g = nt*512 + us*16 + (lane&15);
    const unsigned short* wp = Wbf + ((size_t)dir*2048 + g)*512 + kh*256 + (lane>>4)*8;
    #pragma unroll
    for (int kt=0;kt<8;kt++) bfr[kt] = *(const short8*)(wp + kt*32);
  }

  float p0=0,p1=0,p2=0,p3=0,q0=0,q1=0,q2=0,q3=0;
  float creg = 0.f, hprev = 0.f;
  int bg = 0, ug = 0;
  if (tid < 256){
    bg = b0 + (tid>>4);
    ug = us*16 + (tid&15);
    const float* P = PQ + dir*4096; const float* Q = P + 2048;
    p0=P[ug]; p1=P[ug+512]; p2=P[ug+1024]; p3=P[ug+1536];
    q0=Q[ug]; q1=Q[ug+512]; q2=Q[ug+1024]; q3=Q[ug+1536];
  }

  for (int tt=0; tt<512; ++tt){
    const int t = dir ? (511-tt) : tt;
    if (tt>0){
      if (tid==0){
        while (__hip_atomic_load(gcnt, __ATOMIC_RELAXED, AGENT) < 32u*(unsigned)tt)
          __builtin_amdgcn_s_sleep(1);
      }
      __syncthreads();
      const int par = (tt-1)&1;
      f32x4 tmp0, tmp1;
      {
        const int f0 = tid, f1 = 512 + tid;
        const unsigned short* g0 = hbuf + (((size_t)(dir*2+par)*64 + b0 + (f0>>6))<<9) + (f0&63)*8;
        const unsigned short* g1 = hbuf + (((size_t)(dir*2+par)*64 + b0 + (f1>>6))<<9) + (f1&63)*8;
        asm volatile("global_load_dwordx4 %0, %1, off sc0 sc1" : "=v"(tmp0) : "v"(g0) : "memory");
        asm volatile("global_load_dwordx4 %0, %1, off sc0 sc1" : "=v"(tmp1) : "v"(g1) : "memory");
      }
      asm volatile("s_waitcnt vmcnt(0)" ::: "memory");
      __builtin_amdgcn_sched_barrier(0);
      {
        const int r0 = tid>>6, c0 = tid&63;
        *(f32x4*)&hlds[r0*256 + ((c0 ^ (r0&7))<<2)] = tmp0;
        const int r1 = (512+tid)>>6, c1 = tid&63;
        *(f32x4*)&hlds[r1*256 + ((c1 ^ (r1&7))<<2)] = tmp1;
      }
      __syncthreads();
    }

    f32x4 acc = {0.f,0.f,0.f,0.f};
    if (tt>0){
      #pragma unroll
      for (int kt=0; kt<8; ++kt){
        const int ch = (kh*8 + kt)*4 + (lane>>4);
        V16 a; a.f = *(const f32x4*)&hlds[rowb*256 + ((ch ^ (rowb&7))<<2)];
        acc = __builtin_amdgcn_mfma_f32_16x16x32_bf16(a.s, bfr[kt], acc, 0, 0, 0);
      }
    }
    if (kh==1) *(f32x4*)&red[(nt*64+lane)*4] = acc;
    __syncthreads();
    if (kh==0){
      const f32x4 o = *(const f32x4*)&red[(nt*64+lane)*4];
      #pragma unroll
      for (int i=0;i<4;i++){
        const int r = (lane>>4)*4 + i, c = lane&15;
        gbuf[nt*256 + r*16 + c] = acc[i] + o[i];
      }
    }
    __syncthreads();

    if (tid < 256){
      const float sx = src[bg*512+t]*0.001f;
      const int m = smask[bg*512+t];
      const float gi = gbuf[0*256+tid] + sx*p0 + q0;
      const float gf = gbuf[1*256+tid] + sx*p1 + q1;
      const float gg = gbuf[2*256+tid] + sx*p2 + q2;
      const float go = gbuf[3*256+tid] + sx*p3 + q3;
      const float cn = fmaf(sigm(gf), creg, sigm(gi)*tanhfast(gg));
      const float hn = sigm(go)*tanhfast(cn);
      const float hk = m ? hn : hprev;
      creg = m ? cn : creg;
      hprev = hk;
      hstage[tid] = bfbits(hk);
      estage[tid] = bfbits(m ? hn : 0.f);
    }
    __syncthreads();
    if (tid < 32){
      const int row = tid>>1, hw = tid&1;
      const f32x4 v = *(const f32x4*)(hstage + row*16 + hw*8);
      unsigned short* dst = hbuf + (((size_t)(dir*2+(tt&1))*64 + b0 + row)<<9) + us*16 + hw*8;
      asm volatile("global_store_dwordx4 %0, %1, off sc0 sc1" :: "v"(dst), "v"(v) : "memory");
    } else if (tid < 64){
      const int j = tid-32, row = j>>1, hw = j&1;
      const f32x4 v = *(const f32x4*)(estage + row*16 + hw*8);
      *(f32x4*)((unsigned short*)enc + ((size_t)((b0+row)*512 + t))*1024 + dir*512 + us*16 + hw*8) = v;
    }
    asm volatile("s_waitcnt vmcnt(0)" ::: "memory");
    __syncthreads();
    if (tid==0) __hip_atomic_fetch_add(gcnt, 1u, __ATOMIC_RELAXED, AGENT);
  }

  if (tid < 256){
    hfin[dir*32768 + bg*512 + ug] = hprev;
    (dir ? cb : cf)[bg*512 + ug] = creg;
  }
}

// ---------------- decoder init ----------------
__global__ void __launch_bounds__(256) fc_init(
  const float* __restrict__ hf0, const float* __restrict__ hb0,
  const float* __restrict__ cf, const float* __restrict__ cb,
  const float* __restrict__ fchW, const float* __restrict__ fchB,
  const float* __restrict__ fccW, const float* __restrict__ fccB,
  float* __restrict__ dech, float* __restrict__ decc)
{
  const int which = blockIdx.x >> 7;
  const int wid = blockIdx.x & 127;
  const int b = threadIdx.x >> 2, ul = threadIdx.x & 3;
  const int u = wid*4 + ul;
  const float* s0 = which ? cf : hf0;
  const float* s1 = which ? cb : hb0;
  const float* W = which ? fccW : fchW;
  float acc = (which ? fccB : fchB)[u];
  const float4* x0 = (const float4*)(s0 + b*512);
  const float4* x1 = (const float4*)(s1 + b*512);
  const float4* wr = (const float4*)(W + (size_t)u*1024);
  #pragma unroll 4
  for (int k=0;k<128;k++) acc += dot4(x0[k], wr[k]);
  #pragma unroll 4
  for (int k=0;k<128;k++) acc += dot4(x1[k], wr[128+k]);
  (which ? decc : dech)[b*512+u] = tanhfast(acc);
}

// ---------------- eh2 via MFMA ----------------
__global__ void __launch_bounds__(256) eh_mfma(
  const unsigned short* __restrict__ enc,
  const unsigned short* __restrict__ Wencb,
  unsigned short* __restrict__ eh2)
{
  const int b = blockIdx.x>>6, st = (blockIdx.x>>3)&7, nt0 = blockIdx.x&7;
  const int wv = threadIdx.x>>6, lane = threadIdx.x&63;
  const int sA = st*64 + wv*16 + (lane&15);
  const int kb = (lane>>4)*8;
  const unsigned short* ap  = enc + ((size_t)(b*512 + sA))*1024 + kb;
  const unsigned short* bp0 = Wencb + ((size_t)(nt0*64 + (lane&15)))*1024 + kb;
  f32x4 acc[4] = {{0,0,0,0},{0,0,0,0},{0,0,0,0},{0,0,0,0}};
  for (int k0=0; k0<1024; k0+=32){
    V16 a; a.f = *(const f32x4*)(ap + k0);
    #pragma unroll
    for (int nt=0; nt<4; ++nt){
      V16 bb; bb.f = *(const f32x4*)(bp0 + (size_t)nt*16*1024 + k0);
      acc[nt] = __builtin_amdgcn_mfma_f32_16x16x32_bf16(a.s, bb.s, acc[nt], 0, 0, 0);
    }
  }
  const int sO = st*64 + wv*16 + (lane>>4)*4;
  const int col = lane&15;
  #pragma unroll
  for (int nt=0; nt<4; ++nt){
    #pragma unroll
    for (int i=0;i<4;i++){
      eh2[((size_t)(b*512 + sO + i))*512 + nt0*64 + nt*16 + col] = bfbits(acc[nt][i]);
    }
  }
}

// ---------------- encT2[b][j][s] ----------------
__global__ void __launch_bounds__(256) enc_tr(
  const unsigned short* __restrict__ enc, unsigned short* __restrict__ encT2)
{
  __shared__ unsigned short tl[64][80];
  const int b = blockIdx.x>>7, st = (blockIdx.x>>4)&7, jt = blockIdx.x&15;
  const int r = threadIdx.x>>2, q = threadIdx.x&3;
  const unsigned short* src = enc + ((size_t)(b*512 + st*64 + r))*1024 + jt*64 + q*16;
  *(short8*)&tl[r][q*16]   = *(const short8*)src;
  *(short8*)&tl[r][q*16+8] = *(const short8*)(src+8);
  __syncthreads();
  unsigned short tmp[16];
  #pragma unroll
  for (int e=0;e<16;e++) tmp[e] = tl[q*16+e][r];
  unsigned short* dst = encT2 + ((size_t)(b*1024 + jt*64 + r))*512 + st*64 + q*16;
  *(short8*)dst     = *(short8*)&tmp[0];
  *(short8*)(dst+8) = *(short8*)&tmp[8];
}

// ---------------- barriers (counter-based, used by fallback) ----------------
template<int NG>
__device__ __forceinline__ void gbar(unsigned* gctr, unsigned* root, int grp, unsigned gen){
  asm volatile("s_waitcnt vmcnt(0)" ::: "memory");
  __syncthreads();
  if (threadIdx.x==0){
    const unsigned old = __hip_atomic_fetch_add(gctr + grp*32, 1u, __ATOMIC_RELAXED, AGENT);
    if (old == gen*16u - 1u)
      __hip_atomic_fetch_add(root, 1u, __ATOMIC_RELAXED, AGENT);
    while (__hip_atomic_load(root, __ATOMIC_RELAXED, AGENT) < gen*(unsigned)NG)
      __builtin_amdgcn_s_sleep(1);
  }
  __syncthreads();
}
template<int NB>
__device__ __forceinline__ void mbar(unsigned* mc, unsigned mgen){
  asm volatile("s_waitcnt vmcnt(0)" ::: "memory");
  __syncthreads();
  if (threadIdx.x==0){
    __hip_atomic_fetch_add(mc, 1u, __ATOMIC_RELAXED, AGENT);
    while (__hip_atomic_load(mc, __ATOMIC_RELAXED, AGENT) < mgen*(unsigned)NB)
      __builtin_amdgcn_s_sleep(1);
  }
  __syncthreads();
}

// ---------------- flat one-sided barriers (dec512) ----------------
// aflag: 512 flags, 128B apart. Thread i polls block i's flag.
__device__ __forceinline__ void fgbar(unsigned* aflag, unsigned gen){
  asm volatile("s_waitcnt vmcnt(0)" ::: "memory");
  __syncthreads();
  if (threadIdx.x==0)
    __hip_atomic_store(aflag + (size_t)blockIdx.x*32, gen, __ATOMIC_RELAXED, AGENT);
  {
    unsigned v = __hip_atomic_load(aflag + (size_t)threadIdx.x*32, __ATOMIC_RELAXED, AGENT);
    while (v < gen){
      __builtin_amdgcn_s_sleep(2);
      v = __hip_atomic_load(aflag + (size_t)threadIdx.x*32, __ATOMIC_RELAXED, AGENT);
    }
  }
  __syncthreads();
}
// mflag: 64 groups x 8 flags, 128B apart; threads 0-7 poll.
__device__ __forceinline__ void fmbar(unsigned* mflag, int b, int oct, unsigned gen){
  asm volatile("s_waitcnt vmcnt(0)" ::: "memory");
  __syncthreads();
  if (threadIdx.x==0)
    __hip_atomic_store(mflag + (size_t)(b*8+oct)*32, gen, __ATOMIC_RELAXED, AGENT);
  if (threadIdx.x < 8){
    unsigned v = __hip_atomic_load(mflag + (size_t)(b*8+(int)threadIdx.x)*32, __ATOMIC_RELAXED, AGENT);
    while (v < gen){
      __builtin_amdgcn_s_sleep(1);
      v = __hip_atomic_load(mflag + (size_t)(b*8+(int)threadIdx.x)*32, __ATOMIC_RELAXED, AGENT);
    }
  }
  __syncthreads();
}

// ---------------- dec256 fallback (round-9 proven structure) ----------------
__global__ void __launch_bounds__(512) dec_fused256(
  const float* __restrict__ trg, const int* __restrict__ smask,
  const float* __restrict__ attnv,
  const unsigned short* __restrict__ eh2,
  const unsigned short* __restrict__ encT2,
  const unsigned short* __restrict__ Wcat,
  const unsigned short* __restrict__ Wdecb,
  const float* __restrict__ PQd, const float* __restrict__ hc,
  const float* __restrict__ valW, const float* __restrict__ stopW,
  const float* __restrict__ dech0, const float* __restrict__ decc0,
  float* __restrict__ scorep, float* __restrict__ ctxf,
  unsigned short* __restrict__ xbuf, float* __restrict__ gates,
  float* __restrict__ hcur, float* __restrict__ out,
  unsigned* __restrict__ gctr, unsigned* __restrict__ root, unsigned* __restrict__ mctr,
  unsigned* __restrict__ aflag, unsigned* __restrict__ mflag)
{
  __shared__ alignas(16) float redl[8192];
  __shared__ float vlds[512];
  __shared__ float hldsa[512];
  __shared__ float adhl[128];
  __shared__ float wlds[512];
  const int tid = threadIdx.x;
  const int bid = blockIdx.x;
  const int b = bid>>2, quad = bid&3;
  const int grp = bid>>4;
  const int lane = tid&63, wv = tid>>6;
  unsigned* mc = mctr + b*32;
  unsigned g = 0, m = 0;
  (void)aflag; (void)mflag;

  vlds[tid] = attnv[tid];

  short8 gw[6];
  if (bid < 128){
    const int n = bid*16 + (lane&15);
    const unsigned short* wp = Wcat + (size_t)n*1536 + wv*192 + (lane>>4)*8;
    #pragma unroll
    for (int ks=0;ks<6;ks++) gw[ks] = *(const short8*)(wp + ks*32);
  }

  const bool isb = (quad==0);
  float hr=0.f, cr=0.f;
  float pqi=0,pqf=0,pqg=0,pqo=0, qqi=0,qqf=0,qqg=0,qqo=0;
  float vwh=0,vwc0=0,vwc1=0, swh=0,swc0=0,swc1=0;
  if (isb){
    hr = dech0[b*512+tid]; cr = decc0[b*512+tid];
    pqi = PQd[tid];      pqf = PQd[512+tid];      pqg = PQd[1024+tid];      pqo = PQd[1536+tid];
    qqi = PQd[2048+tid]; qqf = PQd[2048+512+tid]; qqg = PQd[2048+1024+tid]; qqo = PQd[2048+1536+tid];
    vwh = valW[tid]; vwc0 = valW[512+tid]; vwc1 = valW[1024+tid];
    swh = stopW[tid]; swc0 = stopW[512+tid]; swc1 = stopW[1024+tid];
  }

  if (isb){
    const unsigned hb16 = (unsigned)bfbits(hr);
    unsigned short* xp = xbuf + b*1536 + 1024 + tid;
    asm volatile("global_store_short %0, %1, off sc0 sc1" :: "v"(xp), "v"(hb16) : "memory");
    float* hp = hcur + b*512 + tid;
    asm volatile("global_store_dword %0, %1, off sc0 sc1" :: "v"(hp), "v"(hr) : "memory");
  }
  ++m; mbar<4>(mc, m);

  for (int t=0; t<95; ++t){
    {
      float hv; const float* hp = hcur + b*512 + tid;
      asm volatile("global_load_dword %0, %1, off sc0 sc1\ns_waitcnt vmcnt(0)" : "=v"(hv) : "v"(hp) : "memory");
      hldsa[tid] = hv;
      __syncthreads();
      {
        const int jl = tid>>2, uc = tid&3;
        const unsigned short* wp = Wdecb + (size_t)(quad*128 + jl)*512 + uc*128;
        float a = 0.f;
        #pragma unroll
        for (int i=0;i<16;i++){
          const short8 w8 = *(const short8*)(wp + i*8);
          #pragma unroll
          for (int e=0;e<8;e++)
            a = fmaf(hldsa[uc*128 + i*8 + e], bfu2f((unsigned short)w8[e]), a);
        }
        redl[tid] = a;
      }
      __syncthreads();
      if (tid < 128)
        adhl[tid] = redl[tid*4] + redl[tid*4+1] + redl[tid*4+2] + redl[tid*4+3];
      __syncthreads();
      {
        const unsigned short* ep = eh2 + ((size_t)(b*512 + tid))*512 + quad*128;
        float part = 0.f;
        #pragma unroll
        for (int i=0;i<16;i++){
          const short8 e8 = *(const short8*)(ep + i*8);
          #pragma unroll
          for (int e=0;e<8;e++){
            const int n = i*8 + e;
            part = fmaf(vlds[quad*128+n], tanhfast(adhl[n] + bfu2f((unsigned short)e8[e])), part);
          }
        }
        float* sp = scorep + (size_t)bid*512 + tid;
        asm volatile("global_store_dword %0, %1, off sc0 sc1" :: "v"(sp), "v"(part) : "memory");
      }
    }
    ++m; mbar<4>(mc, m);

    {
      float pa, pb, pc, pd;
      const float* pp = scorep + (size_t)(b*4)*512 + tid;
      asm volatile("global_load_dword %0, %1, off sc0 sc1" : "=v"(pa) : "v"(pp) : "memory");
      asm volatile("global_load_dword %0, %1, off sc0 sc1" : "=v"(pb) : "v"(pp+512) : "memory");
      asm volatile("global_load_dword %0, %1, off sc0 sc1" : "=v"(pc) : "v"(pp+1024) : "memory");
      asm volatile("global_load_dword %0, %1, off sc0 sc1" : "=v"(pd) : "v"(pp+1536) : "memory");
      asm volatile("s_waitcnt vmcnt(0)" ::: "memory");
      __builtin_amdgcn_sched_barrier(0);
      float s0 = (pa+pb)+(pc+pd);
      s0 = smask[b*512+tid] ? s0 : -1.0e9f;
      redl[512+tid] = s0;
      __syncthreads();
      for (int off=256; off>0; off>>=1){
        if (tid<off) redl[512+tid] = fmaxf(redl[512+tid], redl[512+tid+off]);
        __syncthreads();
      }
      const float mx = redl[512];
      __syncthreads();
      const float e = __expf(s0 - mx);
      redl[512+tid] = e;
      __syncthreads();
      for (int off=256; off>0; off>>=1){
        if (tid<off) redl[512+tid] += redl[512+tid+off];
        __syncthreads();
      }
      const float Z = redl[512];
      __syncthreads();
      wlds[tid] = e / Z;
      __syncthreads();
      {
        const int jj = tid>>1, sh = tid&1;
        const unsigned short* cp = encT2 + ((size_t)(b*1024 + quad*256 + jj))*512 + sh*256;
        float c = 0.f;
        #pragma unroll
        for (int i=0;i<32;i++){
          const short8 c8 = *(const short8*)(cp + i*8);
          #pragma unroll
          for (int e2=0;e2<8;e2++)
            c = fmaf(wlds[sh*256 + i*8 + e2], bfu2f((unsigned short)c8[e2]), c);
        }
        redl[tid] = c;
      }
      __syncthreads();
      if (tid < 256){
        const float cv = redl[tid*2] + redl[tid*2+1];
        const int j = quad*256 + tid;
        float* cp2 = ctxf + b*1024 + j;
        asm volatile("global_store_dword %0, %1, off sc0 sc1" :: "v"(cp2), "v"(cv) : "memory");
        const unsigned cb16 = (unsigned)bfbits(cv);
        unsigned short* xp = xbuf + b*1536 + j;
        asm volatile("global_store_short %0, %1, off sc0 sc1" :: "v"(xp), "v"(cb16) : "memory");
      }
    }
    ++g; gbar<16>(gctr, root, grp, g);

    if (bid < 128){
      f32x4 av[2][6];
      f32x4 acc[4] = {{0,0,0,0},{0,0,0,0},{0,0,0,0},{0,0,0,0}};
      {
        const unsigned short* xp0 = xbuf + (size_t)(lane&15)*1536 + wv*192 + (lane>>4)*8;
        #pragma unroll
        for (int ks=0;ks<6;ks++){
          const unsigned short* p = xp0 + ks*32;
          asm volatile("global_load_dwordx4 %0, %1, off sc0 sc1" : "=v"(av[0][ks]) : "v"(p) : "memory");
        }
      }
      #pragma unroll
      for (int mt=0; mt<4; ++mt){
        if (mt<3){
          const unsigned short* xpn = xbuf + (size_t)((mt+1)*16 + (lane&15))*1536 + wv*192 + (lane>>4)*8;
          #pragma unroll
          for (int ks=0;ks<6;ks++){
            const unsigned short* p = xpn + ks*32;
            asm volatile("global_load_dwordx4 %0, %1, off sc0 sc1" : "=v"(av[(mt+1)&1][ks]) : "v"(p) : "memory");
          }
          asm volatile("s_waitcnt vmcnt(6)" ::: "memory");
        } else {
          asm volatile("s_waitcnt vmcnt(0)" ::: "memory");
        }
        __builtin_amdgcn_sched_barrier(0);
        #pragma unroll
        for (int ks=0;ks<6;ks++){
          V16 a; a.f = av[mt&1][ks];
          acc[mt] = __builtin_amdgcn_mfma_f32_16x16x32_bf16(a.s, gw[ks], acc[mt], 0, 0, 0);
        }
      }
      #pragma unroll
      for (int mt=0; mt<4; ++mt)
        *(f32x4*)&redl[wv*1024 + lane*16 + mt*4] = acc[mt];
    }
    __syncthreads();
    if (bid < 128){
      #pragma unroll
      for (int h2=0; h2<2; ++h2){
        const int o = h2*512 + tid;
        const int ob = o>>4, col = o&15;
        const int mt = ob>>4, row = ob&15;
        const int base = (((row>>2)<<4) | col)*16 + mt*4 + (row&3);
        float gsum = 0.f;
        #pragma unroll
        for (int w2=0; w2<8; ++w2) gsum += redl[w2*1024 + base];
        float* gp = gates + ob*2048 + bid*16 + col;
        asm volatile("global_store_dword %0, %1, off sc0 sc1" :: "v"(gp), "v"(gsum) : "memory");
      }
    }
    ++g; gbar<16>(gctr, root, grp, g);

    if (isb){
      float g4[4], c0v, c1v;
      {
        const float* gp = gates + b*2048 + tid;
        const float* cp = ctxf + b*1024 + tid;
        asm volatile("global_load_dword %0, %1, off sc0 sc1" : "=v"(g4[0]) : "v"(gp) : "memory");
        asm volatile("global_load_dword %0, %1, off sc0 sc1" : "=v"(g4[1]) : "v"(gp+512) : "memory");
        asm volatile("global_load_dword %0, %1, off sc0 sc1" : "=v"(g4[2]) : "v"(gp+1024) : "memory");
        asm volatile("global_load_dword %0, %1, off sc0 sc1" : "=v"(g4[3]) : "v"(gp+1536) : "memory");
        asm volatile("global_load_dword %0, %1, off sc0 sc1" : "=v"(c0v) : "v"(cp) : "memory");
        asm volatile("global_load_dword %0, %1, off sc0 sc1" : "=v"(c1v) : "v"(cp+512) : "memory");
        asm volatile("s_waitcnt vmcnt(0)" ::: "memory");
        __builtin_amdgcn_sched_barrier(0);
      }
      const float x = trg[b*96 + t]*0.001f;
      const float gi = g4[0] + x*pqi + qqi;
      const float gf = g4[1] + x*pqf + qqf;
      const float gg = g4[2] + x*pqg + qqg;
      const float go = g4[3] + x*pqo + qqo;
      const float cn = fmaf(sigm(gf), cr, sigm(gi)*tanhfast(gg));
      const float hn = sigm(go)*tanhfast(cn);
      cr = cn; hr = hn;
      const unsigned hb16 = (unsigned)bfbits(hn);
      unsigned short* xp = xbuf + b*1536 + 1024 + tid;
      asm volatile("global_store_short %0, %1, off sc0 sc1" :: "v"(xp), "v"(hb16) : "memory");
      float* hp = hcur + b*512 + tid;
      asm volatile("global_store_dword %0, %1, off sc0 sc1" :: "v"(hp), "v"(hn) : "memory");
      redl[512+tid]  = fmaf(hn, vwh, fmaf(c0v, vwc0, c1v*vwc1));
      redl[1024+tid] = fmaf(hn, swh, fmaf(c0v, swc0, c1v*swc1));
      __syncthreads();
      for (int off=256; off>0; off>>=1){
        if (tid<off){ redl[512+tid]+=redl[512+tid+off]; redl[1024+tid]+=redl[1024+tid+off]; }
        __syncthreads();
      }
      if (tid==0){
        out[b*95 + t] = (redl[512] + x*hc[0] + hc[1])*1000.f;
        out[6080 + b*95 + t] = redl[1024] + x*hc[2] + hc[3];
      }
    }
    ++m; mbar<4>(mc, m);
  }
}

// ---------------- dec512 v3: flat barriers + replicated cell update ----------------
__global__ void __launch_bounds__(512, 4) dec_fused512(
  const float* __restrict__ trg, const int* __restrict__ smask,
  const float* __restrict__ attnv,
  const unsigned short* __restrict__ eh2,    // [64][512 s][512 n]
  const unsigned short* __restrict__ encT2,  // [64][1024 j][512 s]
  const unsigned short* __restrict__ Wcat,
  const unsigned short* __restrict__ Wdecb,  // [512 j][512 u]
  const float* __restrict__ PQd, const float* __restrict__ hc,
  const float* __restrict__ valW, const float* __restrict__ stopW,
  const float* __restrict__ dech0, const float* __restrict__ decc0,
  float* __restrict__ scorep, float* __restrict__ ctxf,
  unsigned short* __restrict__ xbuf, float* __restrict__ gates,
  float* __restrict__ hcur, float* __restrict__ out,
  unsigned* __restrict__ gctr, unsigned* __restrict__ root, unsigned* __restrict__ mctr,
  unsigned* __restrict__ aflag, unsigned* __restrict__ mflag)
{
  __shared__ unsigned short eh2l[32768];      // [n 64][s 512] n-major, 64 KB
  __shared__ alignas(16) float redl[2048];    // phase-shared scratch
  __shared__ float vlds[512];
  __shared__ float hl[512];                   // replicated h state
  __shared__ float adhl[64];
  __shared__ int slen_sh;
  const int tid = threadIdx.x;
  const int bid = blockIdx.x;
  const int b = bid>>3, oct = bid&7;
  const int lane = tid&63, wv = tid>>6;
  unsigned g = 0, m = 0;
  (void)gctr; (void)root; (void)mctr; (void)hcur;

  vlds[tid] = attnv[tid];

  // per-b valid length (smask prefix-form)
  redl[tid] = (float)smask[b*512+tid];
  __syncthreads();
  for (int off=256; off>0; off>>=1){
    if (tid<off) redl[tid] += redl[tid+off];
    __syncthreads();
  }
  if (tid==0) slen_sh = (int)(redl[0]+0.5f);
  __syncthreads();
  const int slen = slen_sh;
  const int nch = (slen + 127) >> 7;

  // fill eh2l
  {
    const unsigned short* ep = eh2 + ((size_t)(b*512 + tid))*512 + oct*64;
    short8 r8[8];
    #pragma unroll
    for (int i=0;i<8;i++) r8[i] = *(const short8*)(ep + i*8);
    #pragma unroll
    for (int i=0;i<8;i++)
      #pragma unroll
      for (int e=0;e<8;e++)
        eh2l[(i*8+e)*512 + tid] = (unsigned short)r8[i][e];
  }

  short8 gw[6];
  if (bid < 128){
    const int n = bid*16 + (lane&15);
    const unsigned short* wp = Wcat + (size_t)n*1536 + wv*192 + (lane>>4)*8;
    #pragma unroll
    for (int ks=0;ks<6;ks++) gw[ks] = *(const short8*)(wp + ks*32);
  }

  const bool isb = (oct==0);
  // cell-update constants: ALL blocks (replicated update)
  float cr = decc0[b*512+tid];
  const float pqi = PQd[tid],      pqf = PQd[512+tid],      pqg = PQd[1024+tid],      pqo = PQd[1536+tid];
  const float qqi = PQd[2048+tid], qqf = PQd[2048+512+tid], qqg = PQd[2048+1024+tid], qqo = PQd[2048+1536+tid];
  float vwh=0,vwc0=0,vwc1=0, swh=0,swc0=0,swc1=0;
  if (isb){
    vwh = valW[tid]; vwc0 = valW[512+tid]; vwc1 = valW[1024+tid];
    swh = stopW[tid]; swc0 = stopW[512+tid]; swc1 = stopW[1024+tid];
  }

  // seed h (replicated) + xbuf h-half (oct0)
  {
    const float h0 = dech0[b*512+tid];
    hl[tid] = h0;
    if (isb){
      const unsigned hb16 = (unsigned)bfbits(h0);
      unsigned short* xp = xbuf + b*1536 + 1024 + tid;
      asm volatile("global_store_short %0, %1, off sc0 sc1" :: "v"(xp), "v"(hb16) : "memory");
    }
  }
  __syncthreads();

  for (int t=0; t<95; ++t){
    // ---- Phase A: ADH + score partials (h from LDS, eh2 from LDS) ----
    {
      {
        const int jl = tid>>3, uc = tid&7;
        const unsigned short* wp = Wdecb + (size_t)(oct*64 + jl)*512 + uc*64;
        float a = 0.f;
        #pragma unroll
        for (int i=0;i<8;i++){
          const short8 w8 = *(const short8*)(wp + i*8);
          #pragma unroll
          for (int e=0;e<8;e++)
            a = fmaf(hl[uc*64 + i*8 + e], bfu2f((unsigned short)w8[e]), a);
        }
        redl[tid] = a;
      }
      __syncthreads();
      if (tid < 64){
        float s8 = 0.f;
        #pragma unroll
        for (int i=0;i<8;i++) s8 += redl[tid*8+i];
        adhl[tid] = s8;
      }
      __syncthreads();
      {
        float part = 0.f;
        #pragma unroll 8
        for (int n=0;n<64;++n)
          part = fmaf(vlds[oct*64+n], tanhfast(adhl[n] + bfu2f(eh2l[n*512 + tid])), part);
        float* sp = scorep + (size_t)bid*512 + tid;
        asm volatile("global_store_dword %0, %1, off sc0 sc1" :: "v"(sp), "v"(part) : "memory");
      }
    }
    ++m; fmbar(mflag, b, oct, m);

    // ---- Phase B: softmax + ctx chunk (len-skip + prefetch) ----
    {
      float ps[8];
      const float* pp = scorep + (size_t)(b*8)*512 + tid;
      #pragma unroll
      for (int i=0;i<8;i++){
        const float* p = pp + i*512;
        asm volatile("global_load_dword %0, %1, off sc0 sc1" : "=v"(ps[i]) : "v"(p) : "memory");
      }
      const int jj = tid>>2, sh = tid&3;
      const bool act = (sh < nch);
      const int she = act ? sh : 0;
      const unsigned short* cp = encT2 + ((size_t)(b*1024 + oct*128 + jj))*512 + she*128;
      f32x4 pre[8];
      #pragma unroll
      for (int i=0;i<8;i++){
        const unsigned short* p = cp + i*8;
        asm volatile("global_load_dwordx4 %0, %1, off" : "=v"(pre[i]) : "v"(p) : "memory");
      }
      asm volatile("s_waitcnt vmcnt(8)" ::: "memory");
      __builtin_amdgcn_sched_barrier(0);
      float s0 = ((ps[0]+ps[1])+(ps[2]+ps[3]))+((ps[4]+ps[5])+(ps[6]+ps[7]));
      s0 = (tid < slen) ? s0 : -1.0e9f;
      redl[512+tid] = s0;
      __syncthreads();
      for (int off=256; off>0; off>>=1){
        if (tid<off) redl[512+tid] = fmaxf(redl[512+tid], redl[512+tid+off]);
        __syncthreads();
      }
      const float mx = redl[512];
      __syncthreads();
      const float e = __expf(s0 - mx);
      redl[512+tid] = e;
      __syncthreads();
      for (int off=256; off>0; off>>=1){
        if (tid<off) redl[512+tid] += redl[512+tid+off];
        __syncthreads();
      }
      const float Z = redl[512];
      __syncthreads();
      redl[1024+tid] = e / Z;
      __syncthreads();
      float c = 0.f;
      asm volatile("s_waitcnt vmcnt(0)" ::: "memory");
      __builtin_amdgcn_sched_barrier(0);
      #pragma unroll
      for (int i=0;i<8;i++){
        V16 x; x.f = pre[i];
        #pragma unroll
        for (int e2=0;e2<8;e2++)
          c = fmaf(redl[1024 + she*128 + i*8 + e2], bfu2f((unsigned short)x.s[e2]), c);
      }
      #pragma unroll
      for (int i=8;i<16;i++){
        const short8 c8 = *(const short8*)(cp + i*8);
        #pragma unroll
        for (int e2=0;e2<8;e2++)
          c = fmaf(redl[1024 + she*128 + i*8 + e2], bfu2f((unsigned short)c8[e2]), c);
      }
      c = act ? c : 0.f;
      redl[tid] = c;
      __syncthreads();
      if (tid < 128){
        const float cv = redl[tid*4] + redl[tid*4+1] + redl[tid*4+2] + redl[tid*4+3];
        const int j = oct*128 + tid;
        float* cp2 = ctxf + b*1024 + j;
        asm volatile("global_store_dword %0, %1, off sc0 sc1" :: "v"(cp2), "v"(cv) : "memory");
        const unsigned cb16 = (unsigned)bfbits(cv);
        unsigned short* xp = xbuf + b*1536 + j;
        asm volatile("global_store_short %0, %1, off sc0 sc1" :: "v"(xp), "v"(cb16) : "memory");
      }
    }
    ++g; fgbar(aflag, g);

    // ---- Phase C: gates MFMA (bid<128), LDS-atomicAdd k-reduction ----
    redl[tid] = 0.f; redl[512+tid] = 0.f;
    __syncthreads();
    if (bid < 128){
      f32x4 av[2][6];
      f32x4 acc[4] = {{0,0,0,0},{0,0,0,0},{0,0,0,0},{0,0,0,0}};
      {
        const unsigned short* xp0 = xbuf + (size_t)(lane&15)*1536 + wv*192 + (lane>>4)*8;
        #pragma unroll
        for (int ks=0;ks<6;ks++){
          const unsigned short* p = xp0 + ks*32;
          asm volatile("global_load_dwordx4 %0, %1, off sc0 sc1" : "=v"(av[0][ks]) : "v"(p) : "memory");
        }
      }
      #pragma unroll
      for (int mt=0; mt<4; ++mt){
        if (mt<3){
          const unsigned short* xpn = xbuf + (size_t)((mt+1)*16 + (lane&15))*1536 + wv*192 + (lane>>4)*8;
          #pragma unroll
          for (int ks=0;ks<6;ks++){
            const unsigned short* p = xpn + ks*32;
            asm volatile("global_load_dwordx4 %0, %1, off sc0 sc1" : "=v"(av[(mt+1)&1][ks]) : "v"(p) : "memory");
          }
          asm volatile("s_waitcnt vmcnt(6)" ::: "memory");
        } else {
          asm volatile("s_waitcnt vmcnt(0)" ::: "memory");
        }
        __builtin_amdgcn_sched_barrier(0);
        #pragma unroll
        for (int ks=0;ks<6;ks++){
          V16 a; a.f = av[mt&1][ks];
          acc[mt] = __builtin_amdgcn_mfma_f32_16x16x32_bf16(a.s, gw[ks], acc[mt], 0, 0, 0);
        }
      }
      #pragma unroll
      for (int mt=0; mt<4; ++mt)
        #pragma unroll
        for (int i=0;i<4;i++){
          const int r = (lane>>4)*4 + i, cc = lane&15;
          atomicAdd(&redl[(mt*16 + r)*16 + cc], acc[mt][i]);
        }
    }
    __syncthreads();
    if (bid < 128){
      #pragma unroll
      for (int h2=0; h2<2; ++h2){
        const int o = h2*512 + tid;
        const int ob = o>>4, col = o&15;
        const float gsum = redl[o];
        float* gp = gates + ob*2048 + bid*16 + col;
        asm volatile("global_store_dword %0, %1, off sc0 sc1" :: "v"(gp), "v"(gsum) : "memory");
      }
    }
    ++g; fgbar(aflag, g);

    // ---- Phase D: replicated cell update (ALL blocks); heads by oct0 ----
    {
      float g4[4], c0v = 0.f, c1v = 0.f;
      {
        const float* gp = gates + b*2048 + tid;
        asm volatile("global_load_dword %0, %1, off sc0 sc1" : "=v"(g4[0]) : "v"(gp) : "memory");
        asm volatile("global_load_dword %0, %1, off sc0 sc1" : "=v"(g4[1]) : "v"(gp+512) : "memory");
        asm volatile("global_load_dword %0, %1, off sc0 sc1" : "=v"(g4[2]) : "v"(gp+1024) : "memory");
        asm volatile("global_load_dword %0, %1, off sc0 sc1" : "=v"(g4[3]) : "v"(gp+1536) : "memory");
        if (isb){
          const float* cp = ctxf + b*1024 + tid;
          asm volatile("global_load_dword %0, %1, off sc0 sc1" : "=v"(c0v) : "v"(cp) : "memory");
          asm volatile("global_load_dword %0, %1, off sc0 sc1" : "=v"(c1v) : "v"(cp+512) : "memory");
        }
        asm volatile("s_waitcnt vmcnt(0)" ::: "memory");
        __builtin_amdgcn_sched_barrier(0);
      }
      const float x = trg[b*96 + t]*0.001f;
      const float gi = g4[0] + x*pqi + qqi;
      const float gf = g4[1] + x*pqf + qqf;
      const float gg = g4[2] + x*pqg + qqg;
      const float go = g4[3] + x*pqo + qqo;
      const float cn = fmaf(sigm(gf), cr, sigm(gi)*tanhfast(gg));
      const float hn = sigm(go)*tanhfast(cn);
      cr = cn;
      __syncthreads();          // redl reuse guard (Phase C -> D)
      hl[tid] = hn;
      if (isb){
        const unsigned hb16 = (unsigned)bfbits(hn);
        unsigned short* xp = xbuf + b*1536 + 1024 + tid;
        asm volatile("global_store_short %0, %1, off sc0 sc1" :: "v"(xp), "v"(hb16) : "memory");
        redl[512+tid]  = fmaf(hn, vwh, fmaf(c0v, vwc0, c1v*vwc1));
        redl[1024+tid] = fmaf(hn, swh, fmaf(c0v, swc0, c1v*swc1));
        __syncthreads();
        for (int off=256; off>0; off>>=1){
          if (tid<off){ redl[512+tid]+=redl[512+tid+off]; redl[1024+tid]+=redl[1024+tid+off]; }
          __syncthreads();
        }
        if (tid==0){
          out[b*95 + t] = (redl[512] + x*hc[0] + hc[1])*1000.f;
          out[6080 + b*95 + t] = redl[1024] + x*hc[2] + hc[3];
        }
      }
      __syncthreads();          // hl ready for next Phase A
    }
    // no barrier: next A uses only block-local state; scorep reuse is fenced by this
    // step's B-gbar (all blocks finished reading scorep before C started).
  }
}

// ---------------- launch ----------------
extern "C" void kernel_launch(void* const* d_in, const int* in_sizes, int n_in,
                              void* d_out, int out_size, void* d_ws, size_t ws_size,
                              hipStream_t stream)
{
  (void)in_sizes; (void)n_in; (void)out_size; (void)ws_size;
  const float* src   = (const float*)d_in[0];
  const int*   smask = (const int*)  d_in[1];
  const float* trg   = (const float*)d_in[2];
  const float* epW   = (const float*)d_in[4];
  const float* epb   = (const float*)d_in[5];
  const float* Wihf  = (const float*)d_in[6];
  const float* Whhf  = (const float*)d_in[7];
  const float* bihf  = (const float*)d_in[8];
  const float* bhhf  = (const float*)d_in[9];
  const float* Wihb  = (const float*)d_in[10];
  const float* Whhb  = (const float*)d_in[11];
  const float* bihb  = (const float*)d_in[12];
  const float* bhhb  = (const float*)d_in[13];
  const float* fchW  = (const float*)d_in[14];
  const float* fchB  = (const float*)d_in[15];
  const float* fccW  = (const float*)d_in[16];
  const float* fccB  = (const float*)d_in[17];
  const float* dpW   = (const float*)d_in[18];
  const float* dpb   = (const float*)d_in[19];
  const float* Wenc  = (const float*)d_in[20];
  const float* Wdec  = (const float*)d_in[21];
  const float* attnv = (const float*)d_in[22];
  const float* dWih  = (const float*)d_in[23];
  const float* dWhh  = (const float*)d_in[24];
  const float* dbih  = (const float*)d_in[25];
  const float* dbhh  = (const float*)d_in[26];
  const float* valW  = (const float*)d_in[27];
  const float* valb  = (const float*)d_in[28];
  const float* stopW = (const float*)d_in[29];
  const float* stopb = (const float*)d_in[30];
  float* out = (float*)d_out;

  // ---- bump allocator ----
  char* ws = (char*)d_ws;
  size_t off = 0;
  auto take = [&](size_t nbytes) -> char* {
    char* p = ws + off;
    off += (nbytes + 255) & ~(size_t)255;
    return p;
  };
  unsigned short* enc   = (unsigned short*)take((size_t)64*512*1024*2);
  unsigned short* eh2   = (unsigned short*)take((size_t)64*512*512*2);
  unsigned short* encT2 = (unsigned short*)take((size_t)64*1024*512*2);
  unsigned short* hbuf  = (unsigned short*)take(2*2*64*512*2);
  unsigned short* Wbf   = (unsigned short*)take((size_t)2*2048*512*2);
  unsigned short* Wcat  = (unsigned short*)take((size_t)2048*1536*2);
  unsigned short* Wdecb = (unsigned short*)take(512*512*2);
  unsigned short* Wencb = (unsigned short*)take(512*1024*2);
  float* WT    = (float*)take((size_t)1024*512*4);
  float* hfin  = (float*)take(2*64*512*4);
  float* cf    = (float*)take(64*512*4);
  float* cb    = (float*)take(64*512*4);
  float* PQ    = (float*)take(6*2048*4);
  float* dech0 = (float*)take(64*512*4);
  float* decc0 = (float*)take(64*512*4);
  float* scorep= (float*)take(512*512*4);
  float* ctxf  = (float*)take(64*1024*4);
  unsigned short* xbuf = (unsigned short*)take(64*1536*2);
  float* gates = (float*)take(64*2048*4);
  float* hcur  = (float*)take(64*512*4);
  float* hc    = (float*)take(256);
  unsigned* cnt  = (unsigned*)take(1024);
  unsigned* gctr = (unsigned*)take(4096);
  unsigned* root = (unsigned*)take(256);
  unsigned* mctr = (unsigned*)take(8192);
  unsigned* aflag = (unsigned*)take(65536);   // 512 x 128B
  unsigned* mflag = (unsigned*)take(65536);   // 512 x 128B
  float* PQd = PQ + 8192;
  (void)hipMemsetAsync(cnt, 0, 1024+4096+256+8192+65536+65536, stream);

  precompute<<<2097, 256, 0, stream>>>(Wenc, Wihf, epW, epb, bihf, bhhf, Wihb, bihb, bhhb,
                                       dWih, dpW, dpb, dbih, dbhh, valW, valb, stopW, stopb,
                                       PQ, WT, hc);
  wconv<<<11776, 512, 0, stream>>>(Whhf, Whhb, dWih, dWhh, Wdec, Wenc, Wbf, Wcat, Wdecb, Wencb);

  {
    void* args[] = { (void*)&src, (void*)&smask, (void*)&Wbf, (void*)&PQ,
                     (void*)&hbuf, (void*)&hfin, (void*)&cf, (void*)&cb, (void*)&enc, (void*)&cnt };
    (void)hipLaunchCooperativeKernel((void*)enc_mfma, dim3(256), dim3(512), args, 0, stream);
  }

  {
    const float* hfF = hfin;
    const float* hbF = hfin + 32768;
    fc_init<<<256, 256, 0, stream>>>(hfF, hbF, cf, cb, fchW, fchB, fccW, fccB, dech0, decc0);
  }
  eh_mfma<<<4096, 256, 0, stream>>>(enc, Wencb, eh2);
  enc_tr<<<8192, 256, 0, stream>>>(enc, encT2);

  {
    void* args[] = { (void*)&trg, (void*)&smask, (void*)&attnv,
                     (void*)&eh2, (void*)&encT2, (void*)&Wcat, (void*)&Wdecb,
                     (void*)&PQd, (void*)&hc, (void*)&valW, (void*)&stopW,
                     (void*)&dech0, (void*)&decc0,
                     (void*)&scorep, (void*)&ctxf,
                     (void*)&xbuf, (void*)&gates, (void*)&hcur, (void*)&out,
                     (void*)&gctr, (void*)&root, (void*)&mctr,
                     (void*)&aflag, (void*)&mflag };
    int nb2 = 0;
    (void)hipOccupancyMaxActiveBlocksPerMultiprocessor(&nb2, dec_fused512, 512, 0);
    hipError_t e512 = hipErrorUnknown;
    if (nb2 >= 2)
      e512 = hipLaunchCooperativeKernel((void*)dec_fused512, dim3(512), dim3(512), args, 0, stream);
    if (e512 != hipSuccess)
      (void)hipLaunchCooperativeKernel((void*)dec_fused256, dim3(256), dim3(512), args, 0, stream);
  }
}